// Round 10
// baseline (248.012 us; speedup 1.0000x reference)
//
#include <hip/hip_runtime.h>
#include <hip/hip_bf16.h>

// ProbAttention (Informer ProbSparse) on MI355X.
// Shapes: queries/keys/values (4, 4096, 8, 64) f32 in (b, l, h, d) layout.
// index_sample (4096, 45) int32. Output context (b, h, 4096, 64) f32.
//
// Pipeline (all fp32 — no fp32 MFMA on CDNA4; precision needed for top-k):
//   K1 compute_m   : m[b,h,l] = max_s(q.k_samp) - sum_s(q.k_samp)/4096
//                    1KB half-block gather, (b,hg)->XCD (L2-resident), DPP
//                    16-lane reduce, batch-9 register pipeline.
//   K2a topk_p1    : per (b,h,512-slice) top-45 candidates (packed u64 keys)
//   K2b topk_p2    : merge 8x45 candidates -> global top-45 (tie: lowest idx)
//   K3a meanv_part : partial sums of v over l (2048 blocks, full chip)
//   K3b meanv_final: reduce 64 partials -> meanv
//   K3c fill       : out[...] = meanv broadcast (32 MB write)
//   K4 scores      : block=(b,h,chunk of 256), 1024 threads (16 waves).
//                    QK^T quad-per-key: K in regs, Q streamed from GLOBAL
//                    (L2-resident, 4 distinct 64B windows/wave/u -> no LDS),
//                    DPP quad reduce; chunk softmax; P@V coalesced V.
//   K5 combine     : merge 16 chunk partials, scatter to out rows m_top[u]

#define NB 4
#define NH 8
#define NL 4096
#define ND 64
#define NS 45          // U = n_top = 45
#define SCALE 0.125f   // 1/sqrt(64)
#define NCHUNK 16
#define CHUNK 256

typedef float floatx4 __attribute__((ext_vector_type(4)));

static __device__ __forceinline__ float neg_inf() { return -__builtin_inff(); }

// VALU-pipe cross-lane add via DPP (no DS traffic).
template <int CTRL>
static __device__ __forceinline__ float dpp_add(float x) {
  int y = __builtin_amdgcn_update_dpp(0, __builtin_bit_cast(int, x), CTRL,
                                      0xF, 0xF, true);
  return x + __builtin_bit_cast(float, y);
}
// Sum over 16 contiguous lanes; every lane ends with the group total.
static __device__ __forceinline__ float red16(float x) {
  x = dpp_add<0x140>(x);  // row_mirror      (fold 16 -> 8)
  x = dpp_add<0x141>(x);  // row_half_mirror (fold 8 -> 4)
  x = dpp_add<0x4E>(x);   // quad_perm [2,3,0,1] = xor2
  x = dpp_add<0xB1>(x);   // quad_perm [1,0,3,2] = xor1
  return x;
}
// Sum over each 4-lane quad (butterfly), all 4 lanes get the quad total.
static __device__ __forceinline__ float red4(float x) {
  x = dpp_add<0xB1>(x);   // xor1
  x = dpp_add<0x4E>(x);   // xor2
  return x;
}

// ---------------- K1: sampled-dot m ----------------
// Block per (b, hg, l-group of 4). Wave w = one l. 16-lane group g = head hg*4+g.
// Per sample: 1KB contiguous K half-block (64 lanes x float4), fully coalesced,
// L2-resident (4MB working set per (b,hg) pinned to one XCD via blockIdx&7).
// Samples processed in 5 batches of 9: all 9 loads issued before compute.
__global__ __launch_bounds__(256) void k_compute_m(
    const float* __restrict__ q, const float* __restrict__ k,
    const int* __restrict__ idxs, float* __restrict__ m_out)
{
  __shared__ int sidx[4][48];
  int gb = blockIdx.x;                 // 8192 blocks
  int pair = gb & 7;                   // (b,hg) -> XCD (round-robin dispatch)
  int b = pair >> 1, hg = pair & 1;
  int lg = gb >> 3;                    // 0..1023
  int t = threadIdx.x, w = t >> 6, lane = t & 63, g = lane >> 4;
  int l = lg * 4 + w;

  if (lane < NS) sidx[w][lane] = idxs[l * NS + lane];  // wave-private row

  // Q: heads hg*4..hg*4+3 of row l, 1KB contiguous. Non-temporal (stream once,
  // don't evict the L2-resident K set).
  const floatx4* q4 =
      (const floatx4*)(q + ((size_t)(b * NL + l) * NH + hg * 4) * ND);
  floatx4 qr = __builtin_nontemporal_load(q4 + lane);

  // K half-block base for this (b,hg): row ki at +512 floats each (1KB).
  const float* kbase = k + ((size_t)b * NL * NH + hg * 4) * ND;

  float mx = neg_inf(), sm = 0.f;
#pragma unroll 1
  for (int s0 = 0; s0 < NS; s0 += 9) {
    floatx4 kr[9];
#pragma unroll
    for (int j = 0; j < 9; j++) {
      int ki = __builtin_amdgcn_readfirstlane(sidx[w][s0 + j]);  // SALU addr
      kr[j] = *((const floatx4*)(kbase + (size_t)ki * 512) + lane);
    }
    float p[9];
#pragma unroll
    for (int j = 0; j < 9; j++) {
      float d = kr[j].x * qr.x + kr[j].y * qr.y + kr[j].z * qr.z + kr[j].w * qr.w;
      p[j] = red16(d);                 // 16-lane dot, VALU-only
    }
    // max3-tree fold + reassociated sum (clang fuses fmaxf pairs to v_max3)
    float m0 = fmaxf(fmaxf(p[0], p[1]), p[2]);
    float m1 = fmaxf(fmaxf(p[3], p[4]), p[5]);
    float m2 = fmaxf(fmaxf(p[6], p[7]), p[8]);
    mx = fmaxf(fmaxf(mx, m0), fmaxf(m1, m2));
    sm += ((p[0] + p[1]) + (p[2] + p[3])) +
          ((p[4] + p[5]) + (p[6] + p[7])) + p[8];
  }
  if ((lane & 15) == 0)
    m_out[((size_t)b * NH + hg * 4 + g) * NL + l] = mx - sm * (1.0f / 4096.0f);
}

// ---------------- K2a: per-slice top-45 candidates ----------------
// Block = (bh, 512-slice). Keys: monotone(float) || ~index (exact tie-break).
__global__ __launch_bounds__(256) void k_topk_p1(
    const float* __restrict__ m_in, unsigned long long* __restrict__ cand)
{
  __shared__ unsigned long long keys[512];
  __shared__ unsigned long long wred[4];
  int blk = blockIdx.x;                // bh*8 + slice
  int bh = blk >> 3, slice = blk & 7;
  int t = threadIdx.x, wid = t >> 6, lane = t & 63;
  int base = slice * 512;
  for (int i = t; i < 512; i += 256) {
    float v = m_in[bh * NL + base + i];
    unsigned u = __float_as_uint(v);
    u ^= (u >> 31) ? 0xFFFFFFFFu : 0x80000000u;  // monotone mapping
    keys[i] = ((unsigned long long)u << 32) | (unsigned)(~(unsigned)(base + i));
  }
  __syncthreads();
  for (int it = 0; it < NS; ++it) {
    unsigned long long k0 = keys[t], k1 = keys[t + 256];
    unsigned long long best = k0 > k1 ? k0 : k1;
#pragma unroll
    for (int off = 32; off; off >>= 1) {
      unsigned long long o = __shfl_xor(best, off);
      if (o > best) best = o;
    }
    if (lane == 0) wred[wid] = best;
    __syncthreads();
    if (t == 0) {
      unsigned long long b0 = wred[0];
      if (wred[1] > b0) b0 = wred[1];
      if (wred[2] > b0) b0 = wred[2];
      if (wred[3] > b0) b0 = wred[3];
      cand[blk * NS + it] = b0;
      int gi = (int)(~(unsigned)(b0 & 0xFFFFFFFFull));
      keys[gi - base] = 0;
    }
    __syncthreads();
  }
}

// ---------------- K2b: merge 8x45 candidates -> top-45 ----------------
__global__ __launch_bounds__(256) void k_topk_p2(
    const unsigned long long* __restrict__ cand, int* __restrict__ mtop)
{
  __shared__ unsigned long long keys[8 * NS];  // 360
  __shared__ unsigned long long wred[4];
  __shared__ unsigned long long sbest;
  int bh = blockIdx.x;
  int t = threadIdx.x, wid = t >> 6, lane = t & 63;
  for (int i = t; i < 8 * NS; i += 256) keys[i] = cand[bh * 8 * NS + i];
  __syncthreads();
  for (int it = 0; it < NS; ++it) {
    unsigned long long best = (t < 8 * NS) ? keys[t] : 0ull;
    if (t + 256 < 8 * NS) {
      unsigned long long k1 = keys[t + 256];
      if (k1 > best) best = k1;
    }
#pragma unroll
    for (int off = 32; off; off >>= 1) {
      unsigned long long o = __shfl_xor(best, off);
      if (o > best) best = o;
    }
    if (lane == 0) wred[wid] = best;
    __syncthreads();
    if (t == 0) {
      unsigned long long b0 = wred[0];
      if (wred[1] > b0) b0 = wred[1];
      if (wred[2] > b0) b0 = wred[2];
      if (wred[3] > b0) b0 = wred[3];
      sbest = b0;
      mtop[bh * NS + it] = (int)(~(unsigned)(b0 & 0xFFFFFFFFull));
    }
    __syncthreads();
    unsigned long long bb = sbest;     // keys are unique -> exact match zeroing
    if (t < 8 * NS && keys[t] == bb) keys[t] = 0;
    if (t + 256 < 8 * NS && keys[t + 256] == bb) keys[t + 256] = 0;
    __syncthreads();
  }
}

// ---------------- K3a: partial mean of v over l ----------------
// grid (32 bh, 64 chunks); block sums 64 consecutive l rows.
__global__ __launch_bounds__(256) void k_meanv_part(
    const float* __restrict__ v, float* __restrict__ vpart)
{
  __shared__ float part[4][ND];
  int bh = blockIdx.x, c = blockIdx.y;
  int b = bh >> 3, h = bh & 7;
  int t = threadIdx.x, d = t & 63, g = t >> 6;
  float a0 = 0.f, a1 = 0.f, a2 = 0.f, a3 = 0.f;
  const float* vb = v + ((size_t)(b * NL + c * 64) * NH + h) * ND + d;
#pragma unroll
  for (int i = 0; i < 4; i++) {
    a0 += vb[(size_t)(g + 4 * (4 * i + 0)) * NH * ND];
    a1 += vb[(size_t)(g + 4 * (4 * i + 1)) * NH * ND];
    a2 += vb[(size_t)(g + 4 * (4 * i + 2)) * NH * ND];
    a3 += vb[(size_t)(g + 4 * (4 * i + 3)) * NH * ND];
  }
  part[g][d] = (a0 + a1) + (a2 + a3);
  __syncthreads();
  if (g == 0) {
    float s = part[0][d] + part[1][d] + part[2][d] + part[3][d];
    vpart[(bh * 64 + c) * ND + d] = s;
  }
}

// ---------------- K3b: reduce partials -> meanv ----------------
__global__ __launch_bounds__(64) void k_meanv_final(
    const float* __restrict__ vpart, float* __restrict__ meanv)
{
  int bh = blockIdx.x, d = threadIdx.x;
  float s = 0.f;
  for (int c = 0; c < 64; c++) s += vpart[(bh * 64 + c) * ND + d];
  meanv[bh * ND + d] = s * (1.0f / 4096.0f);
}

// ---------------- K3c: fill output with meanv ----------------
__global__ __launch_bounds__(256) void k_fill(
    const float* __restrict__ meanv, float4* __restrict__ out4)
{
  const int total = NB * NH * NL * ND / 4;  // 2M float4
  const float4* mv4 = (const float4*)meanv;
  for (int i = blockIdx.x * 256 + threadIdx.x; i < total; i += gridDim.x * 256) {
    int bh = i >> 16;       // 65536 float4 per (b,h)
    int d4 = i & 15;
    out4[i] = mv4[bh * 16 + d4];
  }
}

// ---------------- K4: scores+softmax+PV partials (16 waves/block) ----------------
// Block = (b,h, chunk of 256 keys), 1024 threads = 16 waves.
// Phase B: quad-per-key QK^T; K in regs; Q streamed from GLOBAL (L2-resident,
//          4 distinct 64B windows per wave per u -> one 256B row/iter, no LDS).
// Phase B2: full-chunk softmax per row.  Phase C: P@V, coalesced V, 3 rows/wave.
__global__ __launch_bounds__(1024) void k_scores(
    const float* __restrict__ q, const float* __restrict__ k,
    const float* __restrict__ v, const int* __restrict__ mtop,
    float* __restrict__ mc_out, float* __restrict__ lc_out,
    float* __restrict__ op_out)
{
  __shared__ float SLDS[NS * 260];    // 45 rows, 260-stride (pad) = 46.8KB
  __shared__ int mt[NS];
  __shared__ float mcs[NS], lcs[NS];

  int gb = blockIdx.x;
  int xcd = gb & 7, seq = gb >> 3;    // 512 blocks: 4 bh per XCD
  int bh = xcd * 4 + (seq >> 4);
  int c = seq & 15;
  int b = bh >> 3, h = bh & 7;
  int t = threadIdx.x;                // 0..1023
  int wid = t >> 6, lane = t & 63;

  if (t < NS) mt[t] = mtop[bh * NS + t];
  __syncthreads();

  // Phase B: quad owns key kk; lane holds contiguous 64B segment of K row.
  // Q rows read directly from global per u (wave: 4 distinct 16B addrs x4,
  // 16-lane broadcast each; row is L2-resident across the 16 chunks).
  {
    int kk = wid * 16 + (lane >> 2);   // 0..255 (16 waves x 16 keys)
    int seg = lane & 3;
    const float4* k4 =
        (const float4*)(k + ((size_t)(b * NL + c * CHUNK + kk) * NH + h) * ND)
        + seg * 4;
    float4 k0 = k4[0], k1 = k4[1], k2 = k4[2], k3 = k4[3];
    const float* qbase = q + ((size_t)b * NL * NH + h) * ND + seg * 16;
#pragma unroll 5
    for (int u = 0; u < NS; ++u) {
      int row = __builtin_amdgcn_readfirstlane(mt[u]);   // SALU addr
      const float4* qp = (const float4*)(qbase + (size_t)row * NH * ND);
      float4 a0 = qp[0], a1 = qp[1], a2 = qp[2], a3 = qp[3];
      float dot = a0.x * k0.x + a0.y * k0.y + a0.z * k0.z + a0.w * k0.w
                + a1.x * k1.x + a1.y * k1.y + a1.z * k1.z + a1.w * k1.w
                + a2.x * k2.x + a2.y * k2.y + a2.z * k2.z + a2.w * k2.w
                + a3.x * k3.x + a3.y * k3.y + a3.z * k3.z + a3.w * k3.w;
      dot = red4(dot);                 // quad total, VALU-only
      if (seg == 0) SLDS[u * 260 + kk] = dot * SCALE;
    }
  }
  __syncthreads();

  // Phase B2: per-row chunk softmax (max, exp, sum), exp written back.
  for (int u = wid; u < NS; u += 16) {
    float4 sv = *(const float4*)&SLDS[u * 260 + lane * 4];
    float mx = fmaxf(fmaxf(sv.x, sv.y), fmaxf(sv.z, sv.w));
#pragma unroll
    for (int off = 32; off; off >>= 1) mx = fmaxf(mx, __shfl_xor(mx, off));
    float e0 = expf(sv.x - mx), e1 = expf(sv.y - mx);
    float e2 = expf(sv.z - mx), e3 = expf(sv.w - mx);
    float s = e0 + e1 + e2 + e3;
#pragma unroll
    for (int off = 32; off; off >>= 1) s += __shfl_xor(s, off);
    *(float4*)&SLDS[u * 260 + lane * 4] = make_float4(e0, e1, e2, e3);
    if (lane == 0) { mcs[u] = mx; lcs[u] = s; }
  }
  __syncthreads();

  // Phase C: O_partial = P @ V_chunk. Wave w owns rows u = w+16i; lane = d.
  float acc[3];
#pragma unroll
  for (int i = 0; i < 3; i++) acc[i] = 0.f;
  const float* vbase = v + ((size_t)(b * NL + c * CHUNK) * NH + h) * ND + lane;
  for (int kb = 0; kb < 64; ++kb) {
    float vd0 = vbase[(size_t)(kb * 4 + 0) * NH * ND];
    float vd1 = vbase[(size_t)(kb * 4 + 1) * NH * ND];
    float vd2 = vbase[(size_t)(kb * 4 + 2) * NH * ND];
    float vd3 = vbase[(size_t)(kb * 4 + 3) * NH * ND];
#pragma unroll
    for (int i = 0; i < 3; i++) {
      int u = wid + 16 * i;
      if (u < NS) {
        float4 p4 = *(const float4*)&SLDS[u * 260 + kb * 4];  // broadcast
        acc[i] += p4.x * vd0 + p4.y * vd1 + p4.z * vd2 + p4.w * vd3;
      }
    }
  }
#pragma unroll
  for (int i = 0; i < 3; i++) {
    int u = wid + 16 * i;
    if (u < NS)
      op_out[(((size_t)bh * NCHUNK + c) * NS + u) * ND + lane] = acc[i];
  }
  if (t < NS) {
    mc_out[(bh * NCHUNK + c) * NS + t] = mcs[t];
    lc_out[(bh * NCHUNK + c) * NS + t] = lcs[t];
  }
}

// ---------------- K5: combine partials + scatter ----------------
__global__ __launch_bounds__(256) void k_combine(
    const float* __restrict__ mc, const float* __restrict__ lc,
    const float* __restrict__ op, const int* __restrict__ mtop,
    float* __restrict__ out)
{
  int gw = blockIdx.x * 4 + (threadIdx.x >> 6);  // 1440 waves
  int lane = threadIdx.x & 63;
  int bh = gw / NS, u = gw % NS;
  float M = neg_inf();
  for (int c = 0; c < NCHUNK; c++)
    M = fmaxf(M, mc[(bh * NCHUNK + c) * NS + u]);
  float Lsum = 0.f, O = 0.f;
  for (int c = 0; c < NCHUNK; c++) {
    float e = expf(mc[(bh * NCHUNK + c) * NS + u] - M);
    Lsum += lc[(bh * NCHUNK + c) * NS + u] * e;
    O += op[(((size_t)bh * NCHUNK + c) * NS + u) * ND + lane] * e;
  }
  int row = mtop[bh * NS + u];
  out[((size_t)bh * NL + row) * ND + lane] = O / Lsum;
}

extern "C" void kernel_launch(void* const* d_in, const int* in_sizes, int n_in,
                              void* d_out, int out_size, void* d_ws, size_t ws_size,
                              hipStream_t stream) {
  const float* q = (const float*)d_in[0];
  const float* k = (const float*)d_in[1];
  const float* v = (const float*)d_in[2];
  const int* idxs = (const int*)d_in[3];
  float* out = (float*)d_out;
  float* ws = (float*)d_ws;

  // workspace layout (floats): total ~1.66M floats = 6.62 MB
  float* m_ws  = ws;                    // 131072
  int*   mtop  = (int*)(ws + 131072);   // 1440 ints
  float* meanv = ws + 132512;           // 2048
  float* mc    = ws + 134560;           // 32*16*45 = 23040
  float* lc    = ws + 157600;           // 23040
  float* op    = ws + 180640;           // 32*16*45*64 = 1474560
  // Aliases inside op (consumed before k_scores writes op; serial stream):
  //   vpart: op[0 .. 131072)           (meanv partials)
  //   cand : op[131072 .. 154112)      (topk candidates, 11520 u64)
  float* vpart = op;
  unsigned long long* cand = (unsigned long long*)(op + 131072);

  hipLaunchKernelGGL(k_compute_m,   dim3(8192),      dim3(256),  0, stream, q, k, idxs, m_ws);
  hipLaunchKernelGGL(k_topk_p1,     dim3(256),       dim3(256),  0, stream, m_ws, cand);
  hipLaunchKernelGGL(k_topk_p2,     dim3(32),        dim3(256),  0, stream, cand, mtop);
  hipLaunchKernelGGL(k_meanv_part,  dim3(32, 64),    dim3(256),  0, stream, v, vpart);
  hipLaunchKernelGGL(k_meanv_final, dim3(32),        dim3(64),   0, stream, vpart, meanv);
  hipLaunchKernelGGL(k_fill,        dim3(2048),      dim3(256),  0, stream, meanv, (float4*)out);
  hipLaunchKernelGGL(k_scores,      dim3(512),       dim3(1024), 0, stream, q, k, v, mtop, mc, lc, op);
  hipLaunchKernelGGL(k_combine,     dim3(360),       dim3(256),  0, stream, mc, lc, op, mtop, out);
}

// Round 11
// 177.265 us; speedup vs baseline: 1.3991x; 1.3991x over previous
//
#include <hip/hip_runtime.h>
#include <hip/hip_bf16.h>

// ProbAttention (Informer ProbSparse) on MI355X.
// Shapes: queries/keys/values (4, 4096, 8, 64) f32 in (b, l, h, d) layout.
// index_sample (4096, 45) int32. Output context (b, h, 4096, 64) f32.
//
// 5-kernel fused schedule (all fp32 — no fp32 MFMA on CDNA4; precision
// needed for exact top-k):
//   kA: blocks 0..8191  : compute_m (8 waves/block: wave pair shares one l,
//                         24/21 samples each, LDS merge; 1KB half-block
//                         gather, (b,hg)->XCD L2-resident, DPP reduce)
//       blocks 8192..   : meanv_part (V HBM stream overlaps K L2 gather)
//   kB: topk_p1         : per (b,h,512-slice) top-45 candidates (u64 keys)
//   kC: blocks 0..31    : topk_p2 (merge 8x45 -> top-45, tie: lowest idx)
//       blocks 32..63   : meanv_final
//   kD: blocks 0..511   : scores (16 waves: quad-per-key QK^T from LDS-staged
//                         Q [R10 lesson: LDS broadcast >> L2 for hot small
//                         operands], chunk softmax, P@V) -> partials
//       blocks 512..1023: fill out[...] = meanv (32MB write overlaps)
//   kE: combine 16 chunk partials, scatter to out rows m_top[u]

#define NB 4
#define NH 8
#define NL 4096
#define ND 64
#define NS 45          // U = n_top = 45
#define SCALE 0.125f   // 1/sqrt(64)
#define NCHUNK 16
#define CHUNK 256

typedef float floatx4 __attribute__((ext_vector_type(4)));

static __device__ __forceinline__ float neg_inf() { return -__builtin_inff(); }

// VALU-pipe cross-lane add via DPP (no DS traffic).
template <int CTRL>
static __device__ __forceinline__ float dpp_add(float x) {
  int y = __builtin_amdgcn_update_dpp(0, __builtin_bit_cast(int, x), CTRL,
                                      0xF, 0xF, true);
  return x + __builtin_bit_cast(float, y);
}
// Sum over 16 contiguous lanes; every lane ends with the group total.
static __device__ __forceinline__ float red16(float x) {
  x = dpp_add<0x140>(x);  // row_mirror      (fold 16 -> 8)
  x = dpp_add<0x141>(x);  // row_half_mirror (fold 8 -> 4)
  x = dpp_add<0x4E>(x);   // quad_perm [2,3,0,1] = xor2
  x = dpp_add<0xB1>(x);   // quad_perm [1,0,3,2] = xor1
  return x;
}
// Sum over each 4-lane quad (butterfly), all 4 lanes get the quad total.
static __device__ __forceinline__ float red4(float x) {
  x = dpp_add<0xB1>(x);   // xor1
  x = dpp_add<0x4E>(x);   // xor2
  return x;
}

// One batch of BS sampled dots: issue all BS coalesced 1KB loads, then compute.
template <int BS>
static __device__ __forceinline__ void batch_dot(
    const float* __restrict__ kbase, const int* __restrict__ srow, int s0,
    floatx4 qr, int lane, float& mx, float& sm) {
  floatx4 kr[BS];
#pragma unroll
  for (int j = 0; j < BS; j++) {
    int ki = __builtin_amdgcn_readfirstlane(srow[s0 + j]);  // SALU addr
    kr[j] = *((const floatx4*)(kbase + (size_t)ki * 512) + lane);
  }
  float p[BS];
#pragma unroll
  for (int j = 0; j < BS; j++) {
    float d = kr[j].x * qr.x + kr[j].y * qr.y + kr[j].z * qr.z + kr[j].w * qr.w;
    p[j] = red16(d);                   // 16-lane dot, VALU-only
  }
#pragma unroll
  for (int j = 0; j < BS; j++) { mx = fmaxf(mx, p[j]); sm += p[j]; }
}

// ---------------- kA: compute_m (split-sample) + meanv_part ----------------
__global__ __launch_bounds__(512) void kA_m_meanv(
    const float* __restrict__ q, const float* __restrict__ k,
    const float* __restrict__ v, const int* __restrict__ idxs,
    float* __restrict__ m_out, float* __restrict__ vpart)
{
  __shared__ int sidx[4][48];
  __shared__ float lmx[8][4], lsm[8][4];
  __shared__ float part[8][ND];
  int gb = blockIdx.x;
  int t = threadIdx.x, w = t >> 6, lane = t & 63, g = lane >> 4;

  if (gb < 8192) {
    // ---- compute_m: block = (b, hg, l-group of 4); wave pair (w, w+4) = one l.
    int pair = gb & 7;                 // (b,hg) -> XCD (round-robin dispatch)
    int b = pair >> 1, hg = pair & 1;
    int lg = gb >> 3;                  // 0..1023
    int wl = w & 3;
    int l = lg * 4 + wl;

    if (w < 4 && lane < NS) sidx[w][lane] = idxs[l * NS + lane];

    const floatx4* q4 =
        (const floatx4*)(q + ((size_t)(b * NL + l) * NH + hg * 4) * ND);
    floatx4 qr = __builtin_nontemporal_load(q4 + lane);
    const float* kbase = k + ((size_t)b * NL * NH + hg * 4) * ND;
    const int* srow = sidx[wl];
    __syncthreads();

    float mx = neg_inf(), sm = 0.f;
    if (w < 4) {                       // samples [0,24)
      batch_dot<8>(kbase, srow, 0, qr, lane, mx, sm);
      batch_dot<8>(kbase, srow, 8, qr, lane, mx, sm);
      batch_dot<8>(kbase, srow, 16, qr, lane, mx, sm);
    } else {                           // samples [24,45)
      batch_dot<7>(kbase, srow, 24, qr, lane, mx, sm);
      batch_dot<7>(kbase, srow, 31, qr, lane, mx, sm);
      batch_dot<7>(kbase, srow, 38, qr, lane, mx, sm);
    }
    if ((lane & 15) == 0) { lmx[w][g] = mx; lsm[w][g] = sm; }
    __syncthreads();
    if (w < 4 && (lane & 15) == 0) {
      float MX = fmaxf(lmx[w][g], lmx[w + 4][g]);
      float SM = lsm[w][g] + lsm[w + 4][g];
      m_out[((size_t)b * NH + hg * 4 + g) * NL + l] = MX - SM * (1.0f / 4096.0f);
    }
  } else {
    // ---- meanv_part: idx = (bh, chunk-pair cc of 128 rows), 512 threads.
    int idx = gb - 8192;               // 0..1023
    int bh = idx >> 5, cc = idx & 31;
    int b = bh >> 3, h = bh & 7;
    int d = t & 63, gg = t >> 6;       // 8 row-groups
    float a0 = 0.f, a1 = 0.f, a2 = 0.f, a3 = 0.f;
    const float* vb = v + ((size_t)(b * NL + cc * 128) * NH + h) * ND + d;
#pragma unroll
    for (int i = 0; i < 4; i++) {
      a0 += vb[(size_t)(gg + 8 * (4 * i + 0)) * NH * ND];
      a1 += vb[(size_t)(gg + 8 * (4 * i + 1)) * NH * ND];
      a2 += vb[(size_t)(gg + 8 * (4 * i + 2)) * NH * ND];
      a3 += vb[(size_t)(gg + 8 * (4 * i + 3)) * NH * ND];
    }
    part[gg][d] = (a0 + a1) + (a2 + a3);
    __syncthreads();
    if (gg == 0) {
      float s = 0.f;
#pragma unroll
      for (int j = 0; j < 8; j++) s += part[j][d];
      vpart[(bh * 32 + cc) * ND + d] = s;
    }
  }
}

// ---------------- kB: per-slice top-45 candidates ----------------
// Block = (bh, 512-slice). Keys: monotone(float) || ~index (exact tie-break).
__global__ __launch_bounds__(256) void k_topk_p1(
    const float* __restrict__ m_in, unsigned long long* __restrict__ cand)
{
  __shared__ unsigned long long keys[512];
  __shared__ unsigned long long wred[4];
  int blk = blockIdx.x;                // bh*8 + slice
  int bh = blk >> 3, slice = blk & 7;
  int t = threadIdx.x, wid = t >> 6, lane = t & 63;
  int base = slice * 512;
  for (int i = t; i < 512; i += 256) {
    float v = m_in[bh * NL + base + i];
    unsigned u = __float_as_uint(v);
    u ^= (u >> 31) ? 0xFFFFFFFFu : 0x80000000u;  // monotone mapping
    keys[i] = ((unsigned long long)u << 32) | (unsigned)(~(unsigned)(base + i));
  }
  __syncthreads();
  for (int it = 0; it < NS; ++it) {
    unsigned long long k0 = keys[t], k1 = keys[t + 256];
    unsigned long long best = k0 > k1 ? k0 : k1;
#pragma unroll
    for (int off = 32; off; off >>= 1) {
      unsigned long long o = __shfl_xor(best, off);
      if (o > best) best = o;
    }
    if (lane == 0) wred[wid] = best;
    __syncthreads();
    if (t == 0) {
      unsigned long long b0 = wred[0];
      if (wred[1] > b0) b0 = wred[1];
      if (wred[2] > b0) b0 = wred[2];
      if (wred[3] > b0) b0 = wred[3];
      cand[blk * NS + it] = b0;
      int gi = (int)(~(unsigned)(b0 & 0xFFFFFFFFull));
      keys[gi - base] = 0;
    }
    __syncthreads();
  }
}

// ---------------- kC: topk_p2 (blocks 0..31) + meanv_final (32..63) ----------------
__global__ __launch_bounds__(256) void kC_topk2_meanv(
    const unsigned long long* __restrict__ cand, int* __restrict__ mtop,
    const float* __restrict__ vpart, float* __restrict__ meanv)
{
  __shared__ unsigned long long keys[8 * NS];  // 360
  __shared__ unsigned long long wred[4];
  __shared__ unsigned long long sbest;
  __shared__ float part2[4][ND];
  int gb = blockIdx.x;
  int t = threadIdx.x, wid = t >> 6, lane = t & 63;

  if (gb < 32) {
    int bh = gb;
    for (int i = t; i < 8 * NS; i += 256) keys[i] = cand[bh * 8 * NS + i];
    __syncthreads();
    for (int it = 0; it < NS; ++it) {
      unsigned long long best = (t < 8 * NS) ? keys[t] : 0ull;
      if (t + 256 < 8 * NS) {
        unsigned long long k1 = keys[t + 256];
        if (k1 > best) best = k1;
      }
#pragma unroll
      for (int off = 32; off; off >>= 1) {
        unsigned long long o = __shfl_xor(best, off);
        if (o > best) best = o;
      }
      if (lane == 0) wred[wid] = best;
      __syncthreads();
      if (t == 0) {
        unsigned long long b0 = wred[0];
        if (wred[1] > b0) b0 = wred[1];
        if (wred[2] > b0) b0 = wred[2];
        if (wred[3] > b0) b0 = wred[3];
        sbest = b0;
        mtop[bh * NS + it] = (int)(~(unsigned)(b0 & 0xFFFFFFFFull));
      }
      __syncthreads();
      unsigned long long bb = sbest;   // keys are unique -> exact match zeroing
      if (t < 8 * NS && keys[t] == bb) keys[t] = 0;
      if (t + 256 < 8 * NS && keys[t + 256] == bb) keys[t + 256] = 0;
      __syncthreads();
    }
  } else {
    int bh = gb - 32;
    int d = t & 63, gg = t >> 6;       // 4 groups over 32 chunk-pairs
    float s = 0.f;
#pragma unroll
    for (int i = 0; i < 8; i++) s += vpart[(bh * 32 + gg + 4 * i) * ND + d];
    part2[gg][d] = s;
    __syncthreads();
    if (gg == 0) {
      float tot = part2[0][d] + part2[1][d] + part2[2][d] + part2[3][d];
      meanv[bh * ND + d] = tot * (1.0f / 4096.0f);
    }
  }
}

// ---------------- kD: scores (blocks 0..511) + fill (512..1023) ----------------
// scores: block=(b,h,chunk of 256 keys), 1024 threads = 16 waves.
//   Phase B: quad-per-key QK^T, coalesced K regs, Q broadcast from LDS,
//            DPP quad reduce. Phase B2: chunk softmax. Phase C: P@V.
// fill: grid-stride broadcast of meanv into out (32MB, overlaps with scores).
__global__ __launch_bounds__(1024) void kD_scores_fill(
    const float* __restrict__ q, const float* __restrict__ k,
    const float* __restrict__ v, const int* __restrict__ mtop,
    const float* __restrict__ meanv,
    float* __restrict__ mc_out, float* __restrict__ lc_out,
    float* __restrict__ op_out, float4* __restrict__ out4)
{
  __shared__ float QLDS[NS * ND];     // 45x64 = 11.5KB
  __shared__ float SLDS[NS * 260];    // 45 rows, 260-stride (pad) = 46.8KB
  __shared__ int mt[NS];
  __shared__ float mcs[NS], lcs[NS];

  int gb = blockIdx.x;
  int t = threadIdx.x;                // 0..1023
  int wid = t >> 6, lane = t & 63;

  if (gb >= 512) {
    // ---- fill
    const int total = NB * NH * NL * ND / 4;  // 2M float4
    const float4* mv4 = (const float4*)meanv;
    for (int i = (gb - 512) * 1024 + t; i < total; i += 512 * 1024) {
      int bh = i >> 16;               // 65536 float4 per (b,h)
      out4[i] = mv4[bh * 16 + (i & 15)];
    }
    return;
  }

  int xcd = gb & 7, seq = gb >> 3;    // 512 blocks: 4 bh per XCD
  int bh = xcd * 4 + (seq >> 4);
  int c = seq & 15;
  int b = bh >> 3, h = bh & 7;

  if (t < NS) mt[t] = mtop[bh * NS + t];
  __syncthreads();

  // stage Qr (45 rows) into LDS: 720 float4, one per thread t<720
  const float4* q4 = (const float4*)q;
  float4* QL4 = (float4*)QLDS;
  if (t < NS * 16) {
    int u = t >> 4, j = t & 15;
    QL4[t] = q4[((size_t)(b * NL + mt[u]) * NH + h) * 16 + j];
  }
  __syncthreads();

  // Phase B: quad owns key kk; lane holds contiguous 64B segment of K row.
  {
    int kk = wid * 16 + (lane >> 2);   // 0..255 (16 waves x 16 keys)
    int seg = lane & 3;
    const float4* k4 =
        (const float4*)(k + ((size_t)(b * NL + c * CHUNK + kk) * NH + h) * ND)
        + seg * 4;
    float4 k0 = k4[0], k1 = k4[1], k2 = k4[2], k3 = k4[3];
    const float4* qp = QL4 + seg * 4;
    for (int u = 0; u < NS; ++u) {
      float4 a0 = qp[u * 16 + 0], a1 = qp[u * 16 + 1];
      float4 a2 = qp[u * 16 + 2], a3 = qp[u * 16 + 3];
      float dot = a0.x * k0.x + a0.y * k0.y + a0.z * k0.z + a0.w * k0.w
                + a1.x * k1.x + a1.y * k1.y + a1.z * k1.z + a1.w * k1.w
                + a2.x * k2.x + a2.y * k2.y + a2.z * k2.z + a2.w * k2.w
                + a3.x * k3.x + a3.y * k3.y + a3.z * k3.z + a3.w * k3.w;
      dot = red4(dot);                 // quad total, VALU-only
      if (seg == 0) SLDS[u * 260 + kk] = dot * SCALE;
    }
  }
  __syncthreads();

  // Phase B2: per-row chunk softmax (max, exp, sum), exp written back.
  for (int u = wid; u < NS; u += 16) {
    float4 sv = *(const float4*)&SLDS[u * 260 + lane * 4];
    float mx = fmaxf(fmaxf(sv.x, sv.y), fmaxf(sv.z, sv.w));
#pragma unroll
    for (int off = 32; off; off >>= 1) mx = fmaxf(mx, __shfl_xor(mx, off));
    float e0 = expf(sv.x - mx), e1 = expf(sv.y - mx);
    float e2 = expf(sv.z - mx), e3 = expf(sv.w - mx);
    float s = e0 + e1 + e2 + e3;
#pragma unroll
    for (int off = 32; off; off >>= 1) s += __shfl_xor(s, off);
    *(float4*)&SLDS[u * 260 + lane * 4] = make_float4(e0, e1, e2, e3);
    if (lane == 0) { mcs[u] = mx; lcs[u] = s; }
  }
  __syncthreads();

  // Phase C: O_partial = P @ V_chunk. Wave w owns rows u = w+16i; lane = d.
  float acc[3];
#pragma unroll
  for (int i = 0; i < 3; i++) acc[i] = 0.f;
  const float* vbase = v + ((size_t)(b * NL + c * CHUNK) * NH + h) * ND + lane;
  for (int kb = 0; kb < 64; ++kb) {
    float vd0 = vbase[(size_t)(kb * 4 + 0) * NH * ND];
    float vd1 = vbase[(size_t)(kb * 4 + 1) * NH * ND];
    float vd2 = vbase[(size_t)(kb * 4 + 2) * NH * ND];
    float vd3 = vbase[(size_t)(kb * 4 + 3) * NH * ND];
#pragma unroll
    for (int i = 0; i < 3; i++) {
      int u = wid + 16 * i;
      if (u < NS) {
        float4 p4 = *(const float4*)&SLDS[u * 260 + kb * 4];  // broadcast
        acc[i] += p4.x * vd0 + p4.y * vd1 + p4.z * vd2 + p4.w * vd3;
      }
    }
  }
#pragma unroll
  for (int i = 0; i < 3; i++) {
    int u = wid + 16 * i;
    if (u < NS)
      op_out[(((size_t)bh * NCHUNK + c) * NS + u) * ND + lane] = acc[i];
  }
  if (t < NS) {
    mc_out[(bh * NCHUNK + c) * NS + t] = mcs[t];
    lc_out[(bh * NCHUNK + c) * NS + t] = lcs[t];
  }
}

// ---------------- kE: combine partials + scatter ----------------
__global__ __launch_bounds__(256) void k_combine(
    const float* __restrict__ mc, const float* __restrict__ lc,
    const float* __restrict__ op, const int* __restrict__ mtop,
    float* __restrict__ out)
{
  int gw = blockIdx.x * 4 + (threadIdx.x >> 6);  // 1440 waves
  int lane = threadIdx.x & 63;
  int bh = gw / NS, u = gw % NS;
  float M = neg_inf();
  for (int c = 0; c < NCHUNK; c++)
    M = fmaxf(M, mc[(bh * NCHUNK + c) * NS + u]);
  float Lsum = 0.f, O = 0.f;
  for (int c = 0; c < NCHUNK; c++) {
    float e = expf(mc[(bh * NCHUNK + c) * NS + u] - M);
    Lsum += lc[(bh * NCHUNK + c) * NS + u] * e;
    O += op[(((size_t)bh * NCHUNK + c) * NS + u) * ND + lane] * e;
  }
  int row = mtop[bh * NS + u];
  out[((size_t)bh * NL + row) * ND + lane] = O / Lsum;
}

extern "C" void kernel_launch(void* const* d_in, const int* in_sizes, int n_in,
                              void* d_out, int out_size, void* d_ws, size_t ws_size,
                              hipStream_t stream) {
  const float* q = (const float*)d_in[0];
  const float* k = (const float*)d_in[1];
  const float* v = (const float*)d_in[2];
  const int* idxs = (const int*)d_in[3];
  float* out = (float*)d_out;
  float* ws = (float*)d_ws;

  // workspace layout (floats): total ~1.66M floats = 6.62 MB
  float* m_ws  = ws;                    // 131072
  int*   mtop  = (int*)(ws + 131072);   // 1440 ints
  float* meanv = ws + 132512;           // 2048
  float* mc    = ws + 134560;           // 32*16*45 = 23040
  float* lc    = ws + 157600;           // 23040
  float* op    = ws + 180640;           // 32*16*45*64 = 1474560
  // Aliases inside op (consumed before kD writes op; serial stream):
  //   vpart: op[0 .. 65536)            (meanv partials, 32bh x 32cc x 64d)
  //   cand : op[131072 .. 154112)      (topk candidates, 11520 u64)
  float* vpart = op;
  unsigned long long* cand = (unsigned long long*)(op + 131072);

  hipLaunchKernelGGL(kA_m_meanv,     dim3(8192 + 1024), dim3(512),  0, stream,
                     q, k, v, idxs, m_ws, vpart);
  hipLaunchKernelGGL(k_topk_p1,      dim3(256),         dim3(256),  0, stream,
                     m_ws, cand);
  hipLaunchKernelGGL(kC_topk2_meanv, dim3(64),          dim3(256),  0, stream,
                     cand, mtop, vpart, meanv);
  hipLaunchKernelGGL(kD_scores_fill, dim3(1024),        dim3(1024), 0, stream,
                     q, k, v, mtop, meanv, mc, lc, op, (float4*)out);
  hipLaunchKernelGGL(k_combine,      dim3(360),         dim3(256),  0, stream,
                     mc, lc, op, mtop, out);
}

// Round 12
// 176.281 us; speedup vs baseline: 1.4069x; 1.0056x over previous
//
#include <hip/hip_runtime.h>
#include <hip/hip_bf16.h>

// ProbAttention (Informer ProbSparse) on MI355X.
// Shapes: queries/keys/values (4, 4096, 8, 64) f32 in (b, l, h, d) layout.
// index_sample (4096, 45) int32. Output context (b, h, 4096, 64) f32.
//
// 5-kernel fused schedule (all fp32 — no fp32 MFMA on CDNA4; precision
// needed for exact top-k):
//   kA: blocks 0..8191  : compute_m (R9-proven: 4 waves/block, one l each,
//                         45 samples in batches of 9; 1KB half-block gather,
//                         (b,hg)->XCD L2-resident, DPP reduce)
//       blocks 8192..   : meanv_part (V HBM stream overlaps K L2 gather)
//   kB: topk_p1         : per (b,h,512-slice) top-45 candidates (u64 keys)
//   kC: blocks 0..31    : topk_p2 (merge 8x45 -> top-45, tie: lowest idx)
//       blocks 32..63   : meanv_final
//   kD: blocks 0..511   : scores (16 waves: quad-per-key QK^T from LDS-staged
//                         Q, chunk softmax, P@V) -> partials
//       blocks 512..1023: fill out[...] = meanv (32MB NT write, overlaps)
//   kE: combine 16 chunk partials, scatter to out rows m_top[u]

#define NB 4
#define NH 8
#define NL 4096
#define ND 64
#define NS 45          // U = n_top = 45
#define SCALE 0.125f   // 1/sqrt(64)
#define NCHUNK 16
#define CHUNK 256

typedef float floatx4 __attribute__((ext_vector_type(4)));

static __device__ __forceinline__ float neg_inf() { return -__builtin_inff(); }

// VALU-pipe cross-lane add via DPP (no DS traffic).
template <int CTRL>
static __device__ __forceinline__ float dpp_add(float x) {
  int y = __builtin_amdgcn_update_dpp(0, __builtin_bit_cast(int, x), CTRL,
                                      0xF, 0xF, true);
  return x + __builtin_bit_cast(float, y);
}
// Sum over 16 contiguous lanes; every lane ends with the group total.
static __device__ __forceinline__ float red16(float x) {
  x = dpp_add<0x140>(x);  // row_mirror      (fold 16 -> 8)
  x = dpp_add<0x141>(x);  // row_half_mirror (fold 8 -> 4)
  x = dpp_add<0x4E>(x);   // quad_perm [2,3,0,1] = xor2
  x = dpp_add<0xB1>(x);   // quad_perm [1,0,3,2] = xor1
  return x;
}
// Sum over each 4-lane quad (butterfly), all 4 lanes get the quad total.
static __device__ __forceinline__ float red4(float x) {
  x = dpp_add<0xB1>(x);   // xor1
  x = dpp_add<0x4E>(x);   // xor2
  return x;
}

// ---------------- kA: compute_m (R9 structure) + meanv_part ----------------
// compute_m: block per (b, hg, l-group of 4). Wave w = one l; 16-lane group
// g = head hg*4+g. Per sample: 1KB contiguous K half-block, fully coalesced,
// L2-resident (4MB working set per (b,hg) pinned to one XCD via blockIdx&7).
// 45 samples in 5 batches of 9 (9 loads in flight before compute).
__global__ __launch_bounds__(256) void kA_m_meanv(
    const float* __restrict__ q, const float* __restrict__ k,
    const float* __restrict__ v, const int* __restrict__ idxs,
    float* __restrict__ m_out, float* __restrict__ vpart)
{
  __shared__ int sidx[4][48];
  __shared__ float part[4][ND];
  int gb = blockIdx.x;
  int t = threadIdx.x, w = t >> 6, lane = t & 63, g = lane >> 4;

  if (gb < 8192) {
    // ---- compute_m
    int pair = gb & 7;                 // (b,hg) -> XCD (round-robin dispatch)
    int b = pair >> 1, hg = pair & 1;
    int lg = gb >> 3;                  // 0..1023
    int l = lg * 4 + w;

    if (lane < NS) sidx[w][lane] = idxs[l * NS + lane];  // wave-private row

    const floatx4* q4 =
        (const floatx4*)(q + ((size_t)(b * NL + l) * NH + hg * 4) * ND);
    floatx4 qr = __builtin_nontemporal_load(q4 + lane);
    const float* kbase = k + ((size_t)b * NL * NH + hg * 4) * ND;

    float mx = neg_inf(), sm = 0.f;
#pragma unroll 1
    for (int s0 = 0; s0 < NS; s0 += 9) {
      floatx4 kr[9];
#pragma unroll
      for (int j = 0; j < 9; j++) {
        int ki = __builtin_amdgcn_readfirstlane(sidx[w][s0 + j]);  // SALU addr
        kr[j] = *((const floatx4*)(kbase + (size_t)ki * 512) + lane);
      }
      float p[9];
#pragma unroll
      for (int j = 0; j < 9; j++) {
        float d = kr[j].x * qr.x + kr[j].y * qr.y + kr[j].z * qr.z +
                  kr[j].w * qr.w;
        p[j] = red16(d);               // 16-lane dot, VALU-only
      }
      float m0 = fmaxf(fmaxf(p[0], p[1]), p[2]);
      float m1 = fmaxf(fmaxf(p[3], p[4]), p[5]);
      float m2 = fmaxf(fmaxf(p[6], p[7]), p[8]);
      mx = fmaxf(fmaxf(mx, m0), fmaxf(m1, m2));
      sm += ((p[0] + p[1]) + (p[2] + p[3])) +
            ((p[4] + p[5]) + (p[6] + p[7])) + p[8];
    }
    if ((lane & 15) == 0)
      m_out[((size_t)b * NH + hg * 4 + g) * NL + l] = mx - sm * (1.0f / 4096.0f);
  } else {
    // ---- meanv_part: idx = (bh, chunk of 64 rows), 256 threads.
    int idx = gb - 8192;               // 0..2047
    int bh = idx >> 6, c = idx & 63;
    int b = bh >> 3, h = bh & 7;
    int d = t & 63, gg = t >> 6;
    float a0 = 0.f, a1 = 0.f, a2 = 0.f, a3 = 0.f;
    const float* vb = v + ((size_t)(b * NL + c * 64) * NH + h) * ND + d;
#pragma unroll
    for (int i = 0; i < 4; i++) {
      a0 += vb[(size_t)(gg + 4 * (4 * i + 0)) * NH * ND];
      a1 += vb[(size_t)(gg + 4 * (4 * i + 1)) * NH * ND];
      a2 += vb[(size_t)(gg + 4 * (4 * i + 2)) * NH * ND];
      a3 += vb[(size_t)(gg + 4 * (4 * i + 3)) * NH * ND];
    }
    part[gg][d] = (a0 + a1) + (a2 + a3);
    __syncthreads();
    if (gg == 0) {
      float s = part[0][d] + part[1][d] + part[2][d] + part[3][d];
      vpart[(bh * 64 + c) * ND + d] = s;
    }
  }
}

// ---------------- kB: per-slice top-45 candidates ----------------
// Block = (bh, 512-slice). Keys: monotone(float) || ~index (exact tie-break).
__global__ __launch_bounds__(256) void k_topk_p1(
    const float* __restrict__ m_in, unsigned long long* __restrict__ cand)
{
  __shared__ unsigned long long keys[512];
  __shared__ unsigned long long wred[4];
  int blk = blockIdx.x;                // bh*8 + slice
  int bh = blk >> 3, slice = blk & 7;
  int t = threadIdx.x, wid = t >> 6, lane = t & 63;
  int base = slice * 512;
  for (int i = t; i < 512; i += 256) {
    float v = m_in[bh * NL + base + i];
    unsigned u = __float_as_uint(v);
    u ^= (u >> 31) ? 0xFFFFFFFFu : 0x80000000u;  // monotone mapping
    keys[i] = ((unsigned long long)u << 32) | (unsigned)(~(unsigned)(base + i));
  }
  __syncthreads();
  for (int it = 0; it < NS; ++it) {
    unsigned long long k0 = keys[t], k1 = keys[t + 256];
    unsigned long long best = k0 > k1 ? k0 : k1;
#pragma unroll
    for (int off = 32; off; off >>= 1) {
      unsigned long long o = __shfl_xor(best, off);
      if (o > best) best = o;
    }
    if (lane == 0) wred[wid] = best;
    __syncthreads();
    if (t == 0) {
      unsigned long long b0 = wred[0];
      if (wred[1] > b0) b0 = wred[1];
      if (wred[2] > b0) b0 = wred[2];
      if (wred[3] > b0) b0 = wred[3];
      cand[blk * NS + it] = b0;
      int gi = (int)(~(unsigned)(b0 & 0xFFFFFFFFull));
      keys[gi - base] = 0;
    }
    __syncthreads();
  }
}

// ---------------- kC: topk_p2 (blocks 0..31) + meanv_final (32..63) ----------------
__global__ __launch_bounds__(256) void kC_topk2_meanv(
    const unsigned long long* __restrict__ cand, int* __restrict__ mtop,
    const float* __restrict__ vpart, float* __restrict__ meanv)
{
  __shared__ unsigned long long keys[8 * NS];  // 360
  __shared__ unsigned long long wred[4];
  __shared__ unsigned long long sbest;
  __shared__ float part2[4][ND];
  int gb = blockIdx.x;
  int t = threadIdx.x, wid = t >> 6, lane = t & 63;

  if (gb < 32) {
    int bh = gb;
    for (int i = t; i < 8 * NS; i += 256) keys[i] = cand[bh * 8 * NS + i];
    __syncthreads();
    for (int it = 0; it < NS; ++it) {
      unsigned long long best = (t < 8 * NS) ? keys[t] : 0ull;
      if (t + 256 < 8 * NS) {
        unsigned long long k1 = keys[t + 256];
        if (k1 > best) best = k1;
      }
#pragma unroll
      for (int off = 32; off; off >>= 1) {
        unsigned long long o = __shfl_xor(best, off);
        if (o > best) best = o;
      }
      if (lane == 0) wred[wid] = best;
      __syncthreads();
      if (t == 0) {
        unsigned long long b0 = wred[0];
        if (wred[1] > b0) b0 = wred[1];
        if (wred[2] > b0) b0 = wred[2];
        if (wred[3] > b0) b0 = wred[3];
        sbest = b0;
        mtop[bh * NS + it] = (int)(~(unsigned)(b0 & 0xFFFFFFFFull));
      }
      __syncthreads();
      unsigned long long bb = sbest;   // keys are unique -> exact match zeroing
      if (t < 8 * NS && keys[t] == bb) keys[t] = 0;
      if (t + 256 < 8 * NS && keys[t + 256] == bb) keys[t + 256] = 0;
      __syncthreads();
    }
  } else {
    int bh = gb - 32;
    int d = t & 63, gg = t >> 6;       // 4 groups over 64 chunks
    float s = 0.f;
#pragma unroll
    for (int i = 0; i < 16; i++) s += vpart[(bh * 64 + gg + 4 * i) * ND + d];
    part2[gg][d] = s;
    __syncthreads();
    if (gg == 0) {
      float tot = part2[0][d] + part2[1][d] + part2[2][d] + part2[3][d];
      meanv[bh * ND + d] = tot * (1.0f / 4096.0f);
    }
  }
}

// ---------------- kD: scores (blocks 0..511) + fill (512..1023) ----------------
// scores: block=(b,h,chunk of 256 keys), 1024 threads = 16 waves.
//   Phase B: quad-per-key QK^T, coalesced K regs, Q broadcast from LDS,
//            DPP quad reduce. Phase B2: chunk softmax. Phase C: P@V.
// fill: grid-stride broadcast of meanv into out — NON-TEMPORAL stores so the
//       32MB stream doesn't evict scores' L2-resident K/V/Q.
__global__ __launch_bounds__(1024) void kD_scores_fill(
    const float* __restrict__ q, const float* __restrict__ k,
    const float* __restrict__ v, const int* __restrict__ mtop,
    const float* __restrict__ meanv,
    float* __restrict__ mc_out, float* __restrict__ lc_out,
    float* __restrict__ op_out, float* __restrict__ out)
{
  __shared__ float QLDS[NS * ND];     // 45x64 = 11.5KB
  __shared__ float SLDS[NS * 260];    // 45 rows, 260-stride (pad) = 46.8KB
  __shared__ int mt[NS];
  __shared__ float mcs[NS], lcs[NS];

  int gb = blockIdx.x;
  int t = threadIdx.x;                // 0..1023
  int wid = t >> 6, lane = t & 63;

  if (gb >= 512) {
    // ---- fill (NT stores)
    const int total = NB * NH * NL * ND / 4;  // 2M float4
    const floatx4* mv4 = (const floatx4*)meanv;
    floatx4* o4 = (floatx4*)out;
    for (int i = (gb - 512) * 1024 + t; i < total; i += 512 * 1024) {
      int bh = i >> 16;               // 65536 float4 per (b,h)
      __builtin_nontemporal_store(mv4[bh * 16 + (i & 15)], o4 + i);
    }
    return;
  }

  int xcd = gb & 7, seq = gb >> 3;    // 512 blocks: 4 bh per XCD
  int bh = xcd * 4 + (seq >> 4);
  int c = seq & 15;
  int b = bh >> 3, h = bh & 7;

  if (t < NS) mt[t] = mtop[bh * NS + t];
  __syncthreads();

  // stage Qr (45 rows) into LDS: 720 float4, one per thread t<720
  const float4* q4 = (const float4*)q;
  float4* QL4 = (float4*)QLDS;
  if (t < NS * 16) {
    int u = t >> 4, j = t & 15;
    QL4[t] = q4[((size_t)(b * NL + mt[u]) * NH + h) * 16 + j];
  }
  __syncthreads();

  // Phase B: quad owns key kk; lane holds contiguous 64B segment of K row.
  {
    int kk = wid * 16 + (lane >> 2);   // 0..255 (16 waves x 16 keys)
    int seg = lane & 3;
    const float4* k4 =
        (const float4*)(k + ((size_t)(b * NL + c * CHUNK + kk) * NH + h) * ND)
        + seg * 4;
    float4 k0 = k4[0], k1 = k4[1], k2 = k4[2], k3 = k4[3];
    const float4* qp = QL4 + seg * 4;
    for (int u = 0; u < NS; ++u) {
      float4 a0 = qp[u * 16 + 0], a1 = qp[u * 16 + 1];
      float4 a2 = qp[u * 16 + 2], a3 = qp[u * 16 + 3];
      float dot = a0.x * k0.x + a0.y * k0.y + a0.z * k0.z + a0.w * k0.w
                + a1.x * k1.x + a1.y * k1.y + a1.z * k1.z + a1.w * k1.w
                + a2.x * k2.x + a2.y * k2.y + a2.z * k2.z + a2.w * k2.w
                + a3.x * k3.x + a3.y * k3.y + a3.z * k3.z + a3.w * k3.w;
      dot = red4(dot);                 // quad total, VALU-only
      if (seg == 0) SLDS[u * 260 + kk] = dot * SCALE;
    }
  }
  __syncthreads();

  // Phase B2: per-row chunk softmax (max, exp, sum), exp written back.
  for (int u = wid; u < NS; u += 16) {
    float4 sv = *(const float4*)&SLDS[u * 260 + lane * 4];
    float mx = fmaxf(fmaxf(sv.x, sv.y), fmaxf(sv.z, sv.w));
#pragma unroll
    for (int off = 32; off; off >>= 1) mx = fmaxf(mx, __shfl_xor(mx, off));
    float e0 = expf(sv.x - mx), e1 = expf(sv.y - mx);
    float e2 = expf(sv.z - mx), e3 = expf(sv.w - mx);
    float s = e0 + e1 + e2 + e3;
#pragma unroll
    for (int off = 32; off; off >>= 1) s += __shfl_xor(s, off);
    *(float4*)&SLDS[u * 260 + lane * 4] = make_float4(e0, e1, e2, e3);
    if (lane == 0) { mcs[u] = mx; lcs[u] = s; }
  }
  __syncthreads();

  // Phase C: O_partial = P @ V_chunk. Wave w owns rows u = w+16i; lane = d.
  float acc[3];
#pragma unroll
  for (int i = 0; i < 3; i++) acc[i] = 0.f;
  const float* vbase = v + ((size_t)(b * NL + c * CHUNK) * NH + h) * ND + lane;
  for (int kb = 0; kb < 64; ++kb) {
    float vd0 = vbase[(size_t)(kb * 4 + 0) * NH * ND];
    float vd1 = vbase[(size_t)(kb * 4 + 1) * NH * ND];
    float vd2 = vbase[(size_t)(kb * 4 + 2) * NH * ND];
    float vd3 = vbase[(size_t)(kb * 4 + 3) * NH * ND];
#pragma unroll
    for (int i = 0; i < 3; i++) {
      int u = wid + 16 * i;
      if (u < NS) {
        float4 p4 = *(const float4*)&SLDS[u * 260 + kb * 4];  // broadcast
        acc[i] += p4.x * vd0 + p4.y * vd1 + p4.z * vd2 + p4.w * vd3;
      }
    }
  }
#pragma unroll
  for (int i = 0; i < 3; i++) {
    int u = wid + 16 * i;
    if (u < NS)
      op_out[(((size_t)bh * NCHUNK + c) * NS + u) * ND + lane] = acc[i];
  }
  if (t < NS) {
    mc_out[(bh * NCHUNK + c) * NS + t] = mcs[t];
    lc_out[(bh * NCHUNK + c) * NS + t] = lcs[t];
  }
}

// ---------------- kE: combine partials + scatter ----------------
__global__ __launch_bounds__(256) void k_combine(
    const float* __restrict__ mc, const float* __restrict__ lc,
    const float* __restrict__ op, const int* __restrict__ mtop,
    float* __restrict__ out)
{
  int gw = blockIdx.x * 4 + (threadIdx.x >> 6);  // 1440 waves
  int lane = threadIdx.x & 63;
  int bh = gw / NS, u = gw % NS;
  float M = neg_inf();
  for (int c = 0; c < NCHUNK; c++)
    M = fmaxf(M, mc[(bh * NCHUNK + c) * NS + u]);
  float Lsum = 0.f, O = 0.f;
  for (int c = 0; c < NCHUNK; c++) {
    float e = expf(mc[(bh * NCHUNK + c) * NS + u] - M);
    Lsum += lc[(bh * NCHUNK + c) * NS + u] * e;
    O += op[(((size_t)bh * NCHUNK + c) * NS + u) * ND + lane] * e;
  }
  int row = mtop[bh * NS + u];
  out[((size_t)bh * NL + row) * ND + lane] = O / Lsum;
}

extern "C" void kernel_launch(void* const* d_in, const int* in_sizes, int n_in,
                              void* d_out, int out_size, void* d_ws, size_t ws_size,
                              hipStream_t stream) {
  const float* q = (const float*)d_in[0];
  const float* k = (const float*)d_in[1];
  const float* v = (const float*)d_in[2];
  const int* idxs = (const int*)d_in[3];
  float* out = (float*)d_out;
  float* ws = (float*)d_ws;

  // workspace layout (floats): total ~1.66M floats = 6.62 MB
  float* m_ws  = ws;                    // 131072
  int*   mtop  = (int*)(ws + 131072);   // 1440 ints
  float* meanv = ws + 132512;           // 2048
  float* mc    = ws + 134560;           // 32*16*45 = 23040
  float* lc    = ws + 157600;           // 23040
  float* op    = ws + 180640;           // 32*16*45*64 = 1474560
  // Aliases inside op (consumed before kD writes op; serial stream):
  //   vpart: op[0 .. 131072)           (meanv partials, 32bh x 64c x 64d)
  //   cand : op[131072 .. 154112)      (topk candidates, 11520 u64)
  float* vpart = op;
  unsigned long long* cand = (unsigned long long*)(op + 131072);

  hipLaunchKernelGGL(kA_m_meanv,     dim3(8192 + 2048), dim3(256),  0, stream,
                     q, k, v, idxs, m_ws, vpart);
  hipLaunchKernelGGL(k_topk_p1,      dim3(256),         dim3(256),  0, stream,
                     m_ws, cand);
  hipLaunchKernelGGL(kC_topk2_meanv, dim3(64),          dim3(256),  0, stream,
                     cand, mtop, vpart, meanv);
  hipLaunchKernelGGL(kD_scores_fill, dim3(1024),        dim3(1024), 0, stream,
                     q, k, v, mtop, meanv, mc, lc, op, out);
  hipLaunchKernelGGL(k_combine,      dim3(360),         dim3(256),  0, stream,
                     mc, lc, op, mtop, out);
}

// Round 13
// 175.376 us; speedup vs baseline: 1.4142x; 1.0052x over previous
//
#include <hip/hip_runtime.h>
#include <hip/hip_bf16.h>

// ProbAttention (Informer ProbSparse) on MI355X.
// Shapes: queries/keys/values (4, 4096, 8, 64) f32 in (b, l, h, d) layout.
// index_sample (4096, 45) int32. Output context (b, h, 4096, 64) f32.
//
// 5-kernel fused schedule (all fp32 — no fp32 MFMA on CDNA4; precision
// needed for exact top-k):
//   kA: blocks 0..8191  : compute_m (4 waves/block, one l each, 45 samples
//                         in batches of 9; 1KB half-block gather,
//                         (b,hg)->XCD L2-resident, DPP reduce)
//       blocks 8192..   : meanv_part (V HBM stream overlaps K L2 gather)
//   kB: topk_p1         : per (b,h,512-slice) top-45 candidates (u64 keys)
//   kC: blocks 0..31    : topk_p2 (merge 8x45 -> top-45, tie: lowest idx)
//       blocks 32..63   : meanv_final
//   kD: blocks 0..511   : scores (16 waves; Phase B: 2-keys-per-quad QK^T
//                         with u-split wave-halves -> Q LDS reads halved;
//                         chunk softmax; P@V) -> partials
//       blocks 512..1023: fill out[...] = meanv (32MB NT write, overlaps)
//   kE: combine 16 chunk partials, scatter to out rows m_top[u]

#define NB 4
#define NH 8
#define NL 4096
#define ND 64
#define NS 45          // U = n_top = 45
#define SCALE 0.125f   // 1/sqrt(64)
#define NCHUNK 16
#define CHUNK 256

typedef float floatx4 __attribute__((ext_vector_type(4)));

static __device__ __forceinline__ float neg_inf() { return -__builtin_inff(); }

// VALU-pipe cross-lane add via DPP (no DS traffic).
template <int CTRL>
static __device__ __forceinline__ float dpp_add(float x) {
  int y = __builtin_amdgcn_update_dpp(0, __builtin_bit_cast(int, x), CTRL,
                                      0xF, 0xF, true);
  return x + __builtin_bit_cast(float, y);
}
// Sum over 16 contiguous lanes; every lane ends with the group total.
static __device__ __forceinline__ float red16(float x) {
  x = dpp_add<0x140>(x);  // row_mirror      (fold 16 -> 8)
  x = dpp_add<0x141>(x);  // row_half_mirror (fold 8 -> 4)
  x = dpp_add<0x4E>(x);   // quad_perm [2,3,0,1] = xor2
  x = dpp_add<0xB1>(x);   // quad_perm [1,0,3,2] = xor1
  return x;
}
// Sum over each 4-lane quad (butterfly), all 4 lanes get the quad total.
static __device__ __forceinline__ float red4(float x) {
  x = dpp_add<0xB1>(x);   // xor1
  x = dpp_add<0x4E>(x);   // xor2
  return x;
}

// ---------------- kA: compute_m (R9 structure) + meanv_part ----------------
__global__ __launch_bounds__(256) void kA_m_meanv(
    const float* __restrict__ q, const float* __restrict__ k,
    const float* __restrict__ v, const int* __restrict__ idxs,
    float* __restrict__ m_out, float* __restrict__ vpart)
{
  __shared__ int sidx[4][48];
  __shared__ float part[4][ND];
  int gb = blockIdx.x;
  int t = threadIdx.x, w = t >> 6, lane = t & 63, g = lane >> 4;

  if (gb < 8192) {
    // ---- compute_m
    int pair = gb & 7;                 // (b,hg) -> XCD (round-robin dispatch)
    int b = pair >> 1, hg = pair & 1;
    int lg = gb >> 3;                  // 0..1023
    int l = lg * 4 + w;

    if (lane < NS) sidx[w][lane] = idxs[l * NS + lane];  // wave-private row

    const floatx4* q4 =
        (const floatx4*)(q + ((size_t)(b * NL + l) * NH + hg * 4) * ND);
    floatx4 qr = __builtin_nontemporal_load(q4 + lane);
    const float* kbase = k + ((size_t)b * NL * NH + hg * 4) * ND;

    float mx = neg_inf(), sm = 0.f;
#pragma unroll 1
    for (int s0 = 0; s0 < NS; s0 += 9) {
      floatx4 kr[9];
#pragma unroll
      for (int j = 0; j < 9; j++) {
        int ki = __builtin_amdgcn_readfirstlane(sidx[w][s0 + j]);  // SALU addr
        kr[j] = *((const floatx4*)(kbase + (size_t)ki * 512) + lane);
      }
      float p[9];
#pragma unroll
      for (int j = 0; j < 9; j++) {
        float d = kr[j].x * qr.x + kr[j].y * qr.y + kr[j].z * qr.z +
                  kr[j].w * qr.w;
        p[j] = red16(d);               // 16-lane dot, VALU-only
      }
      float m0 = fmaxf(fmaxf(p[0], p[1]), p[2]);
      float m1 = fmaxf(fmaxf(p[3], p[4]), p[5]);
      float m2 = fmaxf(fmaxf(p[6], p[7]), p[8]);
      mx = fmaxf(fmaxf(mx, m0), fmaxf(m1, m2));
      sm += ((p[0] + p[1]) + (p[2] + p[3])) +
            ((p[4] + p[5]) + (p[6] + p[7])) + p[8];
    }
    if ((lane & 15) == 0)
      m_out[((size_t)b * NH + hg * 4 + g) * NL + l] = mx - sm * (1.0f / 4096.0f);
  } else {
    // ---- meanv_part: idx = (bh, chunk of 64 rows), 256 threads.
    int idx = gb - 8192;               // 0..2047
    int bh = idx >> 6, c = idx & 63;
    int b = bh >> 3, h = bh & 7;
    int d = t & 63, gg = t >> 6;
    float a0 = 0.f, a1 = 0.f, a2 = 0.f, a3 = 0.f;
    const float* vb = v + ((size_t)(b * NL + c * 64) * NH + h) * ND + d;
#pragma unroll
    for (int i = 0; i < 4; i++) {
      a0 += vb[(size_t)(gg + 4 * (4 * i + 0)) * NH * ND];
      a1 += vb[(size_t)(gg + 4 * (4 * i + 1)) * NH * ND];
      a2 += vb[(size_t)(gg + 4 * (4 * i + 2)) * NH * ND];
      a3 += vb[(size_t)(gg + 4 * (4 * i + 3)) * NH * ND];
    }
    part[gg][d] = (a0 + a1) + (a2 + a3);
    __syncthreads();
    if (gg == 0) {
      float s = part[0][d] + part[1][d] + part[2][d] + part[3][d];
      vpart[(bh * 64 + c) * ND + d] = s;
    }
  }
}

// ---------------- kB: per-slice top-45 candidates ----------------
// Block = (bh, 512-slice). Keys: monotone(float) || ~index (exact tie-break).
__global__ __launch_bounds__(256) void k_topk_p1(
    const float* __restrict__ m_in, unsigned long long* __restrict__ cand)
{
  __shared__ unsigned long long keys[512];
  __shared__ unsigned long long wred[4];
  int blk = blockIdx.x;                // bh*8 + slice
  int bh = blk >> 3, slice = blk & 7;
  int t = threadIdx.x, wid = t >> 6, lane = t & 63;
  int base = slice * 512;
  for (int i = t; i < 512; i += 256) {
    float v = m_in[bh * NL + base + i];
    unsigned u = __float_as_uint(v);
    u ^= (u >> 31) ? 0xFFFFFFFFu : 0x80000000u;  // monotone mapping
    keys[i] = ((unsigned long long)u << 32) | (unsigned)(~(unsigned)(base + i));
  }
  __syncthreads();
  for (int it = 0; it < NS; ++it) {
    unsigned long long k0 = keys[t], k1 = keys[t + 256];
    unsigned long long best = k0 > k1 ? k0 : k1;
#pragma unroll
    for (int off = 32; off; off >>= 1) {
      unsigned long long o = __shfl_xor(best, off);
      if (o > best) best = o;
    }
    if (lane == 0) wred[wid] = best;
    __syncthreads();
    if (t == 0) {
      unsigned long long b0 = wred[0];
      if (wred[1] > b0) b0 = wred[1];
      if (wred[2] > b0) b0 = wred[2];
      if (wred[3] > b0) b0 = wred[3];
      cand[blk * NS + it] = b0;
      int gi = (int)(~(unsigned)(b0 & 0xFFFFFFFFull));
      keys[gi - base] = 0;
    }
    __syncthreads();
  }
}

// ---------------- kC: topk_p2 (blocks 0..31) + meanv_final (32..63) ----------------
__global__ __launch_bounds__(256) void kC_topk2_meanv(
    const unsigned long long* __restrict__ cand, int* __restrict__ mtop,
    const float* __restrict__ vpart, float* __restrict__ meanv)
{
  __shared__ unsigned long long keys[8 * NS];  // 360
  __shared__ unsigned long long wred[4];
  __shared__ unsigned long long sbest;
  __shared__ float part2[4][ND];
  int gb = blockIdx.x;
  int t = threadIdx.x, wid = t >> 6, lane = t & 63;

  if (gb < 32) {
    int bh = gb;
    for (int i = t; i < 8 * NS; i += 256) keys[i] = cand[bh * 8 * NS + i];
    __syncthreads();
    for (int it = 0; it < NS; ++it) {
      unsigned long long best = (t < 8 * NS) ? keys[t] : 0ull;
      if (t + 256 < 8 * NS) {
        unsigned long long k1 = keys[t + 256];
        if (k1 > best) best = k1;
      }
#pragma unroll
      for (int off = 32; off; off >>= 1) {
        unsigned long long o = __shfl_xor(best, off);
        if (o > best) best = o;
      }
      if (lane == 0) wred[wid] = best;
      __syncthreads();
      if (t == 0) {
        unsigned long long b0 = wred[0];
        if (wred[1] > b0) b0 = wred[1];
        if (wred[2] > b0) b0 = wred[2];
        if (wred[3] > b0) b0 = wred[3];
        sbest = b0;
        mtop[bh * NS + it] = (int)(~(unsigned)(b0 & 0xFFFFFFFFull));
      }
      __syncthreads();
      unsigned long long bb = sbest;   // keys are unique -> exact match zeroing
      if (t < 8 * NS && keys[t] == bb) keys[t] = 0;
      if (t + 256 < 8 * NS && keys[t + 256] == bb) keys[t + 256] = 0;
      __syncthreads();
    }
  } else {
    int bh = gb - 32;
    int d = t & 63, gg = t >> 6;       // 4 groups over 64 chunks
    float s = 0.f;
#pragma unroll
    for (int i = 0; i < 16; i++) s += vpart[(bh * 64 + gg + 4 * i) * ND + d];
    part2[gg][d] = s;
    __syncthreads();
    if (gg == 0) {
      float tot = part2[0][d] + part2[1][d] + part2[2][d] + part2[3][d];
      meanv[bh * ND + d] = tot * (1.0f / 4096.0f);
    }
  }
}

// ---------------- kD: scores (blocks 0..511) + fill (512..1023) ----------------
// scores: block=(b,h,chunk of 256 keys), 1024 threads = 16 waves.
//   Phase B: 2 keys per quad, u-split wave-halves (waves 0-7: u<23, 8-15:
//            u>=23) -> per-wave Q LDS reads halved vs 1-key/quad.
//   Phase B2: chunk softmax. Phase C: P@V coalesced V.
// fill: grid-stride broadcast of meanv into out — NON-TEMPORAL stores.
__global__ __launch_bounds__(1024) void kD_scores_fill(
    const float* __restrict__ q, const float* __restrict__ k,
    const float* __restrict__ v, const int* __restrict__ mtop,
    const float* __restrict__ meanv,
    float* __restrict__ mc_out, float* __restrict__ lc_out,
    float* __restrict__ op_out, float* __restrict__ out)
{
  __shared__ float QLDS[NS * ND];     // 45x64 = 11.5KB
  __shared__ float SLDS[NS * 260];    // 45 rows, 260-stride (pad) = 46.8KB
  __shared__ int mt[NS];
  __shared__ float mcs[NS], lcs[NS];

  int gb = blockIdx.x;
  int t = threadIdx.x;                // 0..1023
  int wid = t >> 6, lane = t & 63;

  if (gb >= 512) {
    // ---- fill (NT stores)
    const int total = NB * NH * NL * ND / 4;  // 2M float4
    const floatx4* mv4 = (const floatx4*)meanv;
    floatx4* o4 = (floatx4*)out;
    for (int i = (gb - 512) * 1024 + t; i < total; i += 512 * 1024) {
      int bh = i >> 16;               // 65536 float4 per (b,h)
      __builtin_nontemporal_store(mv4[bh * 16 + (i & 15)], o4 + i);
    }
    return;
  }

  int xcd = gb & 7, seq = gb >> 3;    // 512 blocks: 4 bh per XCD
  int bh = xcd * 4 + (seq >> 4);
  int c = seq & 15;
  int b = bh >> 3, h = bh & 7;

  if (t < NS) mt[t] = mtop[bh * NS + t];
  __syncthreads();

  // stage Qr (45 rows) into LDS: 720 float4, one per thread t<720
  const float4* q4 = (const float4*)q;
  float4* QL4 = (float4*)QLDS;
  if (t < NS * 16) {
    int u = t >> 4, j = t & 15;
    QL4[t] = q4[((size_t)(b * NL + mt[u]) * NH + h) * 16 + j];
  }
  __syncthreads();

  // Phase B: 2 keys per quad; wave-half owns a u-range.
  // Waves 0..7: keys {kk, kk+128}, u in [0,23). Waves 8..15: same keys,
  // u in [23,45). Each quad's 2 K rows live in registers.
  {
    int wh = wid & 7;
    int kk = wh * 16 + (lane >> 2);    // 0..127
    int seg = lane & 3;
    int u0 = (wid < 8) ? 0 : 23;
    int u1 = (wid < 8) ? 23 : NS;
    const float4* kA4 =
        (const float4*)(k + ((size_t)(b * NL + c * CHUNK + kk) * NH + h) * ND)
        + seg * 4;
    const float4* kB4 =
        (const float4*)(k + ((size_t)(b * NL + c * CHUNK + kk + 128) * NH + h) * ND)
        + seg * 4;
    float4 ka0 = kA4[0], ka1 = kA4[1], ka2 = kA4[2], ka3 = kA4[3];
    float4 kb0 = kB4[0], kb1 = kB4[1], kb2 = kB4[2], kb3 = kB4[3];
    const float4* qp = QL4 + seg * 4;
    for (int u = u0; u < u1; ++u) {
      float4 a0 = qp[u * 16 + 0], a1 = qp[u * 16 + 1];
      float4 a2 = qp[u * 16 + 2], a3 = qp[u * 16 + 3];
      float dA = a0.x * ka0.x + a0.y * ka0.y + a0.z * ka0.z + a0.w * ka0.w
               + a1.x * ka1.x + a1.y * ka1.y + a1.z * ka1.z + a1.w * ka1.w
               + a2.x * ka2.x + a2.y * ka2.y + a2.z * ka2.z + a2.w * ka2.w
               + a3.x * ka3.x + a3.y * ka3.y + a3.z * ka3.z + a3.w * ka3.w;
      float dB = a0.x * kb0.x + a0.y * kb0.y + a0.z * kb0.z + a0.w * kb0.w
               + a1.x * kb1.x + a1.y * kb1.y + a1.z * kb1.z + a1.w * kb1.w
               + a2.x * kb2.x + a2.y * kb2.y + a2.z * kb2.z + a2.w * kb2.w
               + a3.x * kb3.x + a3.y * kb3.y + a3.z * kb3.z + a3.w * kb3.w;
      dA = red4(dA);                   // quad totals, VALU-only
      dB = red4(dB);
      if (seg == 0) {
        SLDS[u * 260 + kk] = dA * SCALE;
        SLDS[u * 260 + kk + 128] = dB * SCALE;
      }
    }
  }
  __syncthreads();

  // Phase B2: per-row chunk softmax (max, exp, sum), exp written back.
  for (int u = wid; u < NS; u += 16) {
    float4 sv = *(const float4*)&SLDS[u * 260 + lane * 4];
    float mx = fmaxf(fmaxf(sv.x, sv.y), fmaxf(sv.z, sv.w));
#pragma unroll
    for (int off = 32; off; off >>= 1) mx = fmaxf(mx, __shfl_xor(mx, off));
    float e0 = expf(sv.x - mx), e1 = expf(sv.y - mx);
    float e2 = expf(sv.z - mx), e3 = expf(sv.w - mx);
    float s = e0 + e1 + e2 + e3;
#pragma unroll
    for (int off = 32; off; off >>= 1) s += __shfl_xor(s, off);
    *(float4*)&SLDS[u * 260 + lane * 4] = make_float4(e0, e1, e2, e3);
    if (lane == 0) { mcs[u] = mx; lcs[u] = s; }
  }
  __syncthreads();

  // Phase C: O_partial = P @ V_chunk. Wave w owns rows u = w+16i; lane = d.
  float acc[3];
#pragma unroll
  for (int i = 0; i < 3; i++) acc[i] = 0.f;
  const float* vbase = v + ((size_t)(b * NL + c * CHUNK) * NH + h) * ND + lane;
  for (int kb = 0; kb < 64; ++kb) {
    float vd0 = vbase[(size_t)(kb * 4 + 0) * NH * ND];
    float vd1 = vbase[(size_t)(kb * 4 + 1) * NH * ND];
    float vd2 = vbase[(size_t)(kb * 4 + 2) * NH * ND];
    float vd3 = vbase[(size_t)(kb * 4 + 3) * NH * ND];
#pragma unroll
    for (int i = 0; i < 3; i++) {
      int u = wid + 16 * i;
      if (u < NS) {
        float4 p4 = *(const float4*)&SLDS[u * 260 + kb * 4];  // broadcast
        acc[i] += p4.x * vd0 + p4.y * vd1 + p4.z * vd2 + p4.w * vd3;
      }
    }
  }
#pragma unroll
  for (int i = 0; i < 3; i++) {
    int u = wid + 16 * i;
    if (u < NS)
      op_out[(((size_t)bh * NCHUNK + c) * NS + u) * ND + lane] = acc[i];
  }
  if (t < NS) {
    mc_out[(bh * NCHUNK + c) * NS + t] = mcs[t];
    lc_out[(bh * NCHUNK + c) * NS + t] = lcs[t];
  }
}

// ---------------- kE: combine partials + scatter ----------------
__global__ __launch_bounds__(256) void k_combine(
    const float* __restrict__ mc, const float* __restrict__ lc,
    const float* __restrict__ op, const int* __restrict__ mtop,
    float* __restrict__ out)
{
  int gw = blockIdx.x * 4 + (threadIdx.x >> 6);  // 1440 waves
  int lane = threadIdx.x & 63;
  int bh = gw / NS, u = gw % NS;
  float M = neg_inf();
  for (int c = 0; c < NCHUNK; c++)
    M = fmaxf(M, mc[(bh * NCHUNK + c) * NS + u]);
  float Lsum = 0.f, O = 0.f;
  for (int c = 0; c < NCHUNK; c++) {
    float e = expf(mc[(bh * NCHUNK + c) * NS + u] - M);
    Lsum += lc[(bh * NCHUNK + c) * NS + u] * e;
    O += op[(((size_t)bh * NCHUNK + c) * NS + u) * ND + lane] * e;
  }
  int row = mtop[bh * NS + u];
  out[((size_t)bh * NL + row) * ND + lane] = O / Lsum;
}

extern "C" void kernel_launch(void* const* d_in, const int* in_sizes, int n_in,
                              void* d_out, int out_size, void* d_ws, size_t ws_size,
                              hipStream_t stream) {
  const float* q = (const float*)d_in[0];
  const float* k = (const float*)d_in[1];
  const float* v = (const float*)d_in[2];
  const int* idxs = (const int*)d_in[3];
  float* out = (float*)d_out;
  float* ws = (float*)d_ws;

  // workspace layout (floats): total ~1.66M floats = 6.62 MB
  float* m_ws  = ws;                    // 131072
  int*   mtop  = (int*)(ws + 131072);   // 1440 ints
  float* meanv = ws + 132512;           // 2048
  float* mc    = ws + 134560;           // 32*16*45 = 23040
  float* lc    = ws + 157600;           // 23040
  float* op    = ws + 180640;           // 32*16*45*64 = 1474560
  // Aliases inside op (consumed before kD writes op; serial stream):
  //   vpart: op[0 .. 131072)           (meanv partials, 32bh x 64c x 64d)
  //   cand : op[131072 .. 154112)      (topk candidates, 11520 u64)
  float* vpart = op;
  unsigned long long* cand = (unsigned long long*)(op + 131072);

  hipLaunchKernelGGL(kA_m_meanv,     dim3(8192 + 2048), dim3(256),  0, stream,
                     q, k, v, idxs, m_ws, vpart);
  hipLaunchKernelGGL(k_topk_p1,      dim3(256),         dim3(256),  0, stream,
                     m_ws, cand);
  hipLaunchKernelGGL(kC_topk2_meanv, dim3(64),          dim3(256),  0, stream,
                     cand, mtop, vpart, meanv);
  hipLaunchKernelGGL(kD_scores_fill, dim3(1024),        dim3(1024), 0, stream,
                     q, k, v, mtop, meanv, mc, lc, op, out);
  hipLaunchKernelGGL(k_combine,      dim3(360),         dim3(256),  0, stream,
                     mc, lc, op, mtop, out);
}

// Round 14
// 172.765 us; speedup vs baseline: 1.4355x; 1.0151x over previous
//
#include <hip/hip_runtime.h>
#include <hip/hip_bf16.h>

// ProbAttention (Informer ProbSparse) on MI355X.
// Shapes: queries/keys/values (4, 4096, 8, 64) f32 in (b, l, h, d) layout.
// index_sample (4096, 45) int32. Output context (b, h, 4096, 64) f32.
//
// 5-kernel fused schedule (all fp32 — no fp32 MFMA on CDNA4; precision
// needed for exact top-k):
//   kA: blocks 0..8191  : compute_m (4 waves/block, one l each, 45 samples
//                         in batches of 9; 1KB half-block gather,
//                         (b,hg)->XCD L2-resident, DPP reduce)
//       blocks 8192..   : meanv_part (V HBM stream overlaps K L2 gather)
//   kB: topk_p1         : per (b,h,512-slice) top-45 candidates (u64 keys)
//   kC: blocks 0..31    : topk_p2 (merge 8x45 -> top-45, tie: lowest idx)
//       blocks 32..63   : meanv_final
//   kD: blocks 0..511   : scores (16 waves; Phase B: 2-keys-per-quad QK^T;
//                         chunk softmax; Phase C: 4x4 (key-group x u-group)
//                         wave tiling, register accs, 4-phase LDS combine
//                         -> V chunk read 4x not 16x) -> partials
//       blocks 512..1023: fill out[...] = meanv (32MB NT write, overlaps)
//   kE: combine 16 chunk partials, scatter to out rows m_top[u]

#define NB 4
#define NH 8
#define NL 4096
#define ND 64
#define NS 45          // U = n_top = 45
#define SCALE 0.125f   // 1/sqrt(64)
#define NCHUNK 16
#define CHUNK 256

typedef float floatx4 __attribute__((ext_vector_type(4)));

static __device__ __forceinline__ float neg_inf() { return -__builtin_inff(); }

// VALU-pipe cross-lane add via DPP (no DS traffic).
template <int CTRL>
static __device__ __forceinline__ float dpp_add(float x) {
  int y = __builtin_amdgcn_update_dpp(0, __builtin_bit_cast(int, x), CTRL,
                                      0xF, 0xF, true);
  return x + __builtin_bit_cast(float, y);
}
// Sum over 16 contiguous lanes; every lane ends with the group total.
static __device__ __forceinline__ float red16(float x) {
  x = dpp_add<0x140>(x);  // row_mirror      (fold 16 -> 8)
  x = dpp_add<0x141>(x);  // row_half_mirror (fold 8 -> 4)
  x = dpp_add<0x4E>(x);   // quad_perm [2,3,0,1] = xor2
  x = dpp_add<0xB1>(x);   // quad_perm [1,0,3,2] = xor1
  return x;
}
// Sum over each 4-lane quad (butterfly), all 4 lanes get the quad total.
static __device__ __forceinline__ float red4(float x) {
  x = dpp_add<0xB1>(x);   // xor1
  x = dpp_add<0x4E>(x);   // xor2
  return x;
}

// ---------------- kA: compute_m (R9 structure) + meanv_part ----------------
__global__ __launch_bounds__(256) void kA_m_meanv(
    const float* __restrict__ q, const float* __restrict__ k,
    const float* __restrict__ v, const int* __restrict__ idxs,
    float* __restrict__ m_out, float* __restrict__ vpart)
{
  __shared__ int sidx[4][48];
  __shared__ float part[4][ND];
  int gb = blockIdx.x;
  int t = threadIdx.x, w = t >> 6, lane = t & 63, g = lane >> 4;

  if (gb < 8192) {
    // ---- compute_m
    int pair = gb & 7;                 // (b,hg) -> XCD (round-robin dispatch)
    int b = pair >> 1, hg = pair & 1;
    int lg = gb >> 3;                  // 0..1023
    int l = lg * 4 + w;

    if (lane < NS) sidx[w][lane] = idxs[l * NS + lane];  // wave-private row

    const floatx4* q4 =
        (const floatx4*)(q + ((size_t)(b * NL + l) * NH + hg * 4) * ND);
    floatx4 qr = __builtin_nontemporal_load(q4 + lane);
    const float* kbase = k + ((size_t)b * NL * NH + hg * 4) * ND;

    float mx = neg_inf(), sm = 0.f;
#pragma unroll 1
    for (int s0 = 0; s0 < NS; s0 += 9) {
      floatx4 kr[9];
#pragma unroll
      for (int j = 0; j < 9; j++) {
        int ki = __builtin_amdgcn_readfirstlane(sidx[w][s0 + j]);  // SALU addr
        kr[j] = *((const floatx4*)(kbase + (size_t)ki * 512) + lane);
      }
      float p[9];
#pragma unroll
      for (int j = 0; j < 9; j++) {
        float d = kr[j].x * qr.x + kr[j].y * qr.y + kr[j].z * qr.z +
                  kr[j].w * qr.w;
        p[j] = red16(d);               // 16-lane dot, VALU-only
      }
      float m0 = fmaxf(fmaxf(p[0], p[1]), p[2]);
      float m1 = fmaxf(fmaxf(p[3], p[4]), p[5]);
      float m2 = fmaxf(fmaxf(p[6], p[7]), p[8]);
      mx = fmaxf(fmaxf(mx, m0), fmaxf(m1, m2));
      sm += ((p[0] + p[1]) + (p[2] + p[3])) +
            ((p[4] + p[5]) + (p[6] + p[7])) + p[8];
    }
    if ((lane & 15) == 0)
      m_out[((size_t)b * NH + hg * 4 + g) * NL + l] = mx - sm * (1.0f / 4096.0f);
  } else {
    // ---- meanv_part: idx = (bh, chunk of 64 rows), 256 threads.
    int idx = gb - 8192;               // 0..2047
    int bh = idx >> 6, c = idx & 63;
    int b = bh >> 3, h = bh & 7;
    int d = t & 63, gg = t >> 6;
    float a0 = 0.f, a1 = 0.f, a2 = 0.f, a3 = 0.f;
    const float* vb = v + ((size_t)(b * NL + c * 64) * NH + h) * ND + d;
#pragma unroll
    for (int i = 0; i < 4; i++) {
      a0 += vb[(size_t)(gg + 4 * (4 * i + 0)) * NH * ND];
      a1 += vb[(size_t)(gg + 4 * (4 * i + 1)) * NH * ND];
      a2 += vb[(size_t)(gg + 4 * (4 * i + 2)) * NH * ND];
      a3 += vb[(size_t)(gg + 4 * (4 * i + 3)) * NH * ND];
    }
    part[gg][d] = (a0 + a1) + (a2 + a3);
    __syncthreads();
    if (gg == 0) {
      float s = part[0][d] + part[1][d] + part[2][d] + part[3][d];
      vpart[(bh * 64 + c) * ND + d] = s;
    }
  }
}

// ---------------- kB: per-slice top-45 candidates ----------------
// Block = (bh, 512-slice). Keys: monotone(float) || ~index (exact tie-break).
__global__ __launch_bounds__(256) void k_topk_p1(
    const float* __restrict__ m_in, unsigned long long* __restrict__ cand)
{
  __shared__ unsigned long long keys[512];
  __shared__ unsigned long long wred[4];
  int blk = blockIdx.x;                // bh*8 + slice
  int bh = blk >> 3, slice = blk & 7;
  int t = threadIdx.x, wid = t >> 6, lane = t & 63;
  int base = slice * 512;
  for (int i = t; i < 512; i += 256) {
    float v = m_in[bh * NL + base + i];
    unsigned u = __float_as_uint(v);
    u ^= (u >> 31) ? 0xFFFFFFFFu : 0x80000000u;  // monotone mapping
    keys[i] = ((unsigned long long)u << 32) | (unsigned)(~(unsigned)(base + i));
  }
  __syncthreads();
  for (int it = 0; it < NS; ++it) {
    unsigned long long k0 = keys[t], k1 = keys[t + 256];
    unsigned long long best = k0 > k1 ? k0 : k1;
#pragma unroll
    for (int off = 32; off; off >>= 1) {
      unsigned long long o = __shfl_xor(best, off);
      if (o > best) best = o;
    }
    if (lane == 0) wred[wid] = best;
    __syncthreads();
    if (t == 0) {
      unsigned long long b0 = wred[0];
      if (wred[1] > b0) b0 = wred[1];
      if (wred[2] > b0) b0 = wred[2];
      if (wred[3] > b0) b0 = wred[3];
      cand[blk * NS + it] = b0;
      int gi = (int)(~(unsigned)(b0 & 0xFFFFFFFFull));
      keys[gi - base] = 0;
    }
    __syncthreads();
  }
}

// ---------------- kC: topk_p2 (blocks 0..31) + meanv_final (32..63) ----------------
__global__ __launch_bounds__(256) void kC_topk2_meanv(
    const unsigned long long* __restrict__ cand, int* __restrict__ mtop,
    const float* __restrict__ vpart, float* __restrict__ meanv)
{
  __shared__ unsigned long long keys[8 * NS];  // 360
  __shared__ unsigned long long wred[4];
  __shared__ unsigned long long sbest;
  __shared__ float part2[4][ND];
  int gb = blockIdx.x;
  int t = threadIdx.x, wid = t >> 6, lane = t & 63;

  if (gb < 32) {
    int bh = gb;
    for (int i = t; i < 8 * NS; i += 256) keys[i] = cand[bh * 8 * NS + i];
    __syncthreads();
    for (int it = 0; it < NS; ++it) {
      unsigned long long best = (t < 8 * NS) ? keys[t] : 0ull;
      if (t + 256 < 8 * NS) {
        unsigned long long k1 = keys[t + 256];
        if (k1 > best) best = k1;
      }
#pragma unroll
      for (int off = 32; off; off >>= 1) {
        unsigned long long o = __shfl_xor(best, off);
        if (o > best) best = o;
      }
      if (lane == 0) wred[wid] = best;
      __syncthreads();
      if (t == 0) {
        unsigned long long b0 = wred[0];
        if (wred[1] > b0) b0 = wred[1];
        if (wred[2] > b0) b0 = wred[2];
        if (wred[3] > b0) b0 = wred[3];
        sbest = b0;
        mtop[bh * NS + it] = (int)(~(unsigned)(b0 & 0xFFFFFFFFull));
      }
      __syncthreads();
      unsigned long long bb = sbest;   // keys are unique -> exact match zeroing
      if (t < 8 * NS && keys[t] == bb) keys[t] = 0;
      if (t + 256 < 8 * NS && keys[t + 256] == bb) keys[t + 256] = 0;
      __syncthreads();
    }
  } else {
    int bh = gb - 32;
    int d = t & 63, gg = t >> 6;       // 4 groups over 64 chunks
    float s = 0.f;
#pragma unroll
    for (int i = 0; i < 16; i++) s += vpart[(bh * 64 + gg + 4 * i) * ND + d];
    part2[gg][d] = s;
    __syncthreads();
    if (gg == 0) {
      float tot = part2[0][d] + part2[1][d] + part2[2][d] + part2[3][d];
      meanv[bh * ND + d] = tot * (1.0f / 4096.0f);
    }
  }
}

// ---------------- kD: scores (blocks 0..511) + fill (512..1023) ----------------
// scores: block=(b,h,chunk of 256 keys), 1024 threads = 16 waves.
//   Phase B: 2 keys per quad, u-split wave-halves.
//   Phase B2: chunk softmax.
//   Phase C: wave (kg,ug)=(wid&3,wid>>2) owns key-quarter kg x u-group ug;
//            register accs (lane=d); V rows read once per 4 waves (not 16);
//            4-phase combine into QLDS (retired after Phase B), then one
//            float4 copy to op_out.
// fill: grid-stride broadcast of meanv into out — NON-TEMPORAL stores.
__global__ __launch_bounds__(1024) void kD_scores_fill(
    const float* __restrict__ q, const float* __restrict__ k,
    const float* __restrict__ v, const int* __restrict__ mtop,
    const float* __restrict__ meanv,
    float* __restrict__ mc_out, float* __restrict__ lc_out,
    float* __restrict__ op_out, float* __restrict__ out)
{
  __shared__ float QLDS[NS * ND];     // 45x64 = 11.5KB (Q, then O-combine)
  __shared__ float SLDS[NS * 260];    // 45 rows, 260-stride (pad) = 46.8KB
  __shared__ int mt[NS];
  __shared__ float mcs[NS], lcs[NS];

  int gb = blockIdx.x;
  int t = threadIdx.x;                // 0..1023
  int wid = t >> 6, lane = t & 63;

  if (gb >= 512) {
    // ---- fill (NT stores)
    const int total = NB * NH * NL * ND / 4;  // 2M float4
    const floatx4* mv4 = (const floatx4*)meanv;
    floatx4* o4 = (floatx4*)out;
    for (int i = (gb - 512) * 1024 + t; i < total; i += 512 * 1024) {
      int bh = i >> 16;               // 65536 float4 per (b,h)
      __builtin_nontemporal_store(mv4[bh * 16 + (i & 15)], o4 + i);
    }
    return;
  }

  int xcd = gb & 7, seq = gb >> 3;    // 512 blocks: 4 bh per XCD
  int bh = xcd * 4 + (seq >> 4);
  int c = seq & 15;
  int b = bh >> 3, h = bh & 7;

  if (t < NS) mt[t] = mtop[bh * NS + t];
  __syncthreads();

  // stage Qr (45 rows) into LDS: 720 float4, one per thread t<720
  const float4* q4 = (const float4*)q;
  float4* QL4 = (float4*)QLDS;
  if (t < NS * 16) {
    int u = t >> 4, j = t & 15;
    QL4[t] = q4[((size_t)(b * NL + mt[u]) * NH + h) * 16 + j];
  }
  __syncthreads();

  // Phase B: 2 keys per quad; wave-half owns a u-range.
  {
    int wh = wid & 7;
    int kk = wh * 16 + (lane >> 2);    // 0..127
    int seg = lane & 3;
    int u0 = (wid < 8) ? 0 : 23;
    int u1 = (wid < 8) ? 23 : NS;
    const float4* kA4 =
        (const float4*)(k + ((size_t)(b * NL + c * CHUNK + kk) * NH + h) * ND)
        + seg * 4;
    const float4* kB4 =
        (const float4*)(k + ((size_t)(b * NL + c * CHUNK + kk + 128) * NH + h) * ND)
        + seg * 4;
    float4 ka0 = kA4[0], ka1 = kA4[1], ka2 = kA4[2], ka3 = kA4[3];
    float4 kb0 = kB4[0], kb1 = kB4[1], kb2 = kB4[2], kb3 = kB4[3];
    const float4* qp = QL4 + seg * 4;
    for (int u = u0; u < u1; ++u) {
      float4 a0 = qp[u * 16 + 0], a1 = qp[u * 16 + 1];
      float4 a2 = qp[u * 16 + 2], a3 = qp[u * 16 + 3];
      float dA = a0.x * ka0.x + a0.y * ka0.y + a0.z * ka0.z + a0.w * ka0.w
               + a1.x * ka1.x + a1.y * ka1.y + a1.z * ka1.z + a1.w * ka1.w
               + a2.x * ka2.x + a2.y * ka2.y + a2.z * ka2.z + a2.w * ka2.w
               + a3.x * ka3.x + a3.y * ka3.y + a3.z * ka3.z + a3.w * ka3.w;
      float dB = a0.x * kb0.x + a0.y * kb0.y + a0.z * kb0.z + a0.w * kb0.w
               + a1.x * kb1.x + a1.y * kb1.y + a1.z * kb1.z + a1.w * kb1.w
               + a2.x * kb2.x + a2.y * kb2.y + a2.z * kb2.z + a2.w * kb2.w
               + a3.x * kb3.x + a3.y * kb3.y + a3.z * kb3.z + a3.w * kb3.w;
      dA = red4(dA);                   // quad totals, VALU-only
      dB = red4(dB);
      if (seg == 0) {
        SLDS[u * 260 + kk] = dA * SCALE;
        SLDS[u * 260 + kk + 128] = dB * SCALE;
      }
    }
  }
  __syncthreads();

  // Phase B2: per-row chunk softmax (max, exp, sum), exp written back.
  for (int u = wid; u < NS; u += 16) {
    float4 sv = *(const float4*)&SLDS[u * 260 + lane * 4];
    float mx = fmaxf(fmaxf(sv.x, sv.y), fmaxf(sv.z, sv.w));
#pragma unroll
    for (int off = 32; off; off >>= 1) mx = fmaxf(mx, __shfl_xor(mx, off));
    float e0 = expf(sv.x - mx), e1 = expf(sv.y - mx);
    float e2 = expf(sv.z - mx), e3 = expf(sv.w - mx);
    float s = e0 + e1 + e2 + e3;
#pragma unroll
    for (int off = 32; off; off >>= 1) s += __shfl_xor(s, off);
    *(float4*)&SLDS[u * 260 + lane * 4] = make_float4(e0, e1, e2, e3);
    if (lane == 0) { mcs[u] = mx; lcs[u] = s; }
  }
  __syncthreads();

  // Phase C: wave (kg,ug) accumulates O[ug-rows][lane] over key-quarter kg.
  {
    int kg = wid & 3, ug = wid >> 2;
    float acc[12];
#pragma unroll
    for (int i = 0; i < 12; i++) acc[i] = 0.f;
    const float* vbase =
        v + ((size_t)(b * NL + c * CHUNK + kg * 64) * NH + h) * ND + lane;
    const float* prow = &SLDS[kg * 64];
    for (int kb = 0; kb < 16; ++kb) {
      float vd0 = vbase[(size_t)(kb * 4 + 0) * NH * ND];
      float vd1 = vbase[(size_t)(kb * 4 + 1) * NH * ND];
      float vd2 = vbase[(size_t)(kb * 4 + 2) * NH * ND];
      float vd3 = vbase[(size_t)(kb * 4 + 3) * NH * ND];
#pragma unroll
      for (int i = 0; i < 12; i++) {
        int u = ug * 12 + i;
        if (u < NS) {
          float4 p4 = *(const float4*)&prow[u * 260 + kb * 4];  // broadcast
          acc[i] += p4.x * vd0 + p4.y * vd1 + p4.z * vd2 + p4.w * vd3;
        }
      }
    }
    // 4-phase combine into QLDS (Q retired). Phase r: kg==r waves add.
    __syncthreads();                   // all Phase-B/B2 QLDS reads long done
#pragma unroll
    for (int r = 0; r < 4; ++r) {
      if (kg == r) {
#pragma unroll
        for (int i = 0; i < 12; i++) {
          int u = ug * 12 + i;
          if (u < NS) {
            if (r == 0) QLDS[u * ND + lane] = acc[i];
            else        QLDS[u * ND + lane] += acc[i];
          }
        }
      }
      __syncthreads();
    }
  }

  // write op from QLDS (contiguous 45x64), plus mc/lc
  if (t < NS * 16) {
    float4* op4 = (float4*)(op_out + (((size_t)bh * NCHUNK + c) * NS) * ND);
    op4[t] = QL4[t];
  }
  if (t < NS) {
    mc_out[(bh * NCHUNK + c) * NS + t] = mcs[t];
    lc_out[(bh * NCHUNK + c) * NS + t] = lcs[t];
  }
}

// ---------------- kE: combine partials + scatter ----------------
__global__ __launch_bounds__(256) void k_combine(
    const float* __restrict__ mc, const float* __restrict__ lc,
    const float* __restrict__ op, const int* __restrict__ mtop,
    float* __restrict__ out)
{
  int gw = blockIdx.x * 4 + (threadIdx.x >> 6);  // 1440 waves
  int lane = threadIdx.x & 63;
  int bh = gw / NS, u = gw % NS;
  float M = neg_inf();
  for (int c = 0; c < NCHUNK; c++)
    M = fmaxf(M, mc[(bh * NCHUNK + c) * NS + u]);
  float Lsum = 0.f, O = 0.f;
  for (int c = 0; c < NCHUNK; c++) {
    float e = expf(mc[(bh * NCHUNK + c) * NS + u] - M);
    Lsum += lc[(bh * NCHUNK + c) * NS + u] * e;
    O += op[(((size_t)bh * NCHUNK + c) * NS + u) * ND + lane] * e;
  }
  int row = mtop[bh * NS + u];
  out[((size_t)bh * NL + row) * ND + lane] = O / Lsum;
}

extern "C" void kernel_launch(void* const* d_in, const int* in_sizes, int n_in,
                              void* d_out, int out_size, void* d_ws, size_t ws_size,
                              hipStream_t stream) {
  const float* q = (const float*)d_in[0];
  const float* k = (const float*)d_in[1];
  const float* v = (const float*)d_in[2];
  const int* idxs = (const int*)d_in[3];
  float* out = (float*)d_out;
  float* ws = (float*)d_ws;

  // workspace layout (floats): total ~1.66M floats = 6.62 MB
  float* m_ws  = ws;                    // 131072
  int*   mtop  = (int*)(ws + 131072);   // 1440 ints
  float* meanv = ws + 132512;           // 2048
  float* mc    = ws + 134560;           // 32*16*45 = 23040
  float* lc    = ws + 157600;           // 23040
  float* op    = ws + 180640;           // 32*16*45*64 = 1474560
  // Aliases inside op (consumed before kD writes op; serial stream):
  //   vpart: op[0 .. 131072)           (meanv partials, 32bh x 64c x 64d)
  //   cand : op[131072 .. 154112)      (topk candidates, 11520 u64)
  float* vpart = op;
  unsigned long long* cand = (unsigned long long*)(op + 131072);

  hipLaunchKernelGGL(kA_m_meanv,     dim3(8192 + 2048), dim3(256),  0, stream,
                     q, k, v, idxs, m_ws, vpart);
  hipLaunchKernelGGL(k_topk_p1,      dim3(256),         dim3(256),  0, stream,
                     m_ws, cand);
  hipLaunchKernelGGL(kC_topk2_meanv, dim3(64),          dim3(256),  0, stream,
                     cand, mtop, vpart, meanv);
  hipLaunchKernelGGL(kD_scores_fill, dim3(1024),        dim3(1024), 0, stream,
                     q, k, v, mtop, meanv, mc, lc, op, out);
  hipLaunchKernelGGL(k_combine,      dim3(360),         dim3(256),  0, stream,
                     mc, lc, op, mtop, out);
}